// Round 3
// baseline (520.354 us; speedup 1.0000x reference)
//
#include <hip/hip_runtime.h>
#include <cmath>

typedef __bf16 bf16_t;
typedef bf16_t bf16x8 __attribute__((ext_vector_type(8)));
typedef bf16_t bf16x4 __attribute__((ext_vector_type(4)));
typedef float f32x4 __attribute__((ext_vector_type(4)));
typedef short s16x4 __attribute__((ext_vector_type(4)));

#define MFMA16(a, b, c) __builtin_amdgcn_mfma_f32_16x16x32_bf16(a, b, c, 0, 0, 0)

#if defined(__has_builtin)
#if __has_builtin(__builtin_amdgcn_mfma_f32_16x16x16bf16_1k)
#define HAVE_MFMA_1K 1
#endif
#endif

#ifdef HAVE_MFMA_1K
#define MFMA16K16(a, b, c)                                                  \
  __builtin_amdgcn_mfma_f32_16x16x16bf16_1k(                                \
      __builtin_bit_cast(s16x4, a), __builtin_bit_cast(s16x4, b), c, 0, 0, 0)
#else
__device__ __forceinline__ f32x4 mfma16k16_asm(bf16x4 a, bf16x4 b, f32x4 c) {
  asm volatile("s_nop 1\n\tv_mfma_f32_16x16x16_bf16 %0, %1, %2, %0"
               : "+v"(c)
               : "v"(a), "v"(b));
  return c;
}
#define MFMA16K16(a, b, c) mfma16k16_asm(a, b, c)
#endif

#define GLD_TO_LDS(gp, lp)                                                        \
  __builtin_amdgcn_global_load_lds(                                               \
      (const __attribute__((address_space(1))) void*)(gp),                        \
      (__attribute__((address_space(3))) void*)(lp), 16, 0, 0)

__device__ __forceinline__ float loadf(const void* p, size_t i, int isf) {
  return isf ? ((const float*)p)[i] : (float)((const bf16_t*)p)[i];
}

// softmax scale folded into Q: 1/sqrt(64) * log2(e)
#define QSCALE 0.18033688f

// ---------------------------------------------------------------------------
__global__ __launch_bounds__(256) void detect_k(
    const unsigned short* __restrict__ xr, int* __restrict__ flag) {
  __shared__ int s;
  if (threadIdx.x == 0) s = 0;
  __syncthreads();
  int bad = 0;
  for (int i = 0; i < 32; ++i) {
    const unsigned short u = xr[threadIdx.x * 32 + i];
    const int e = (u >> 7) & 0xFF;
    if (e >= 0xC8) bad = 1;
  }
  if (bad) atomicOr(&s, 1);
  __syncthreads();
  if (threadIdx.x == 0) *flag = s;
}

__global__ __launch_bounds__(256) void cvtin_k(const void* __restrict__ src,
                                               bf16_t* __restrict__ dst, int n,
                                               const int* __restrict__ flagp) {
  const int isf = *flagp;
  for (int i = blockIdx.x * 256 + threadIdx.x; i < n; i += gridDim.x * 256)
    dst[i] = (bf16_t)loadf(src, i, isf);
}

__global__ __launch_bounds__(256) void bcat_k(
    const void* bq, const void* bk, const void* bv, const void* bo,
    const void* b1, const void* b2, const void* g1, const void* be1,
    const void* g2, const void* be2, bf16_t* __restrict__ dst,
    const int* __restrict__ flagp) {
  const int isf = *flagp;
  const int i = blockIdx.x * 256 + threadIdx.x;
  if (i >= 9984) return;
  const void* src;
  int off;
  if (i < 768)       { src = bq;  off = i; }
  else if (i < 1536) { src = bk;  off = i - 768; }
  else if (i < 2304) { src = bv;  off = i - 1536; }
  else if (i < 3072) { src = bo;  off = i - 2304; }
  else if (i < 6144) { src = b1;  off = i - 3072; }
  else if (i < 6912) { src = b2;  off = i - 6144; }
  else if (i < 7680) { src = g1;  off = i - 6912; }
  else if (i < 8448) { src = be1; off = i - 7680; }
  else if (i < 9216) { src = g2;  off = i - 8448; }
  else               { src = be2; off = i - 9216; }
  dst[i] = (bf16_t)loadf(src, off, isf);
}

// ---------------------------------------------------------------------------
__global__ __launch_bounds__(256) void wqkv_k(
    const void* __restrict__ Pq, const void* __restrict__ Vq,
    const void* __restrict__ Pk, const void* __restrict__ Vk,
    const void* __restrict__ Pv, const void* __restrict__ Vv,
    bf16_t* __restrict__ Wt, const int* __restrict__ flagp) {
  const int isf = *flagp;
  const int sh = blockIdx.x, s = sh / 12, h = sh % 12;
  const void* P = (s == 0) ? Pq : (s == 1) ? Pk : Pv;
  const void* Vm = (s == 0) ? Vq : (s == 1) ? Vk : Vv;
  __shared__ float Vl[32 * 64];
  const int tid = threadIdx.x;
  for (int i = tid; i < 2048; i += 256)
    Vl[i] = loadf(Vm, (size_t)h * 2048 + i, isf);
  __syncthreads();
  for (int kb = 0; kb < 3; ++kb) {
    const int k = kb * 256 + tid;
    float pr[32];
    const size_t prow = ((size_t)h * 768 + k) * 32;
    for (int r = 0; r < 32; ++r) pr[r] = loadf(P, prow + r, isf);
    for (int e = 0; e < 64; ++e) {
      float a = 0.f;
      for (int r = 0; r < 32; ++r) a += pr[r] * Vl[r * 64 + e];
      Wt[((size_t)sh * 64 + e) * 768 + k] = (bf16_t)a;
    }
  }
}

// ---------------------------------------------------------------------------
__global__ __launch_bounds__(256) void transpose_all_k(
    const void* Uo, const void* Vo, const void* U1, const void* V1,
    const void* U2, const void* V2, bf16_t* UoT, bf16_t* VoT, bf16_t* U1T,
    bf16_t* V1T, bf16_t* U2T, bf16_t* V2T, const int* __restrict__ flagp) {
  const int isf = *flagp;
  int t = blockIdx.x;
  const void* in;
  bf16_t* out;
  int Kd, Nd, bx, by;
  if (t < 192)       { in = Uo; out = UoT; Kd = 768;  Nd = 256;  bx = t & 7;  by = t >> 3; }
  else if (t < 384)  { t -= 192;  in = Vo; out = VoT; Kd = 256;  Nd = 768;  bx = t % 24; by = t / 24; }
  else if (t < 576)  { t -= 384;  in = U1; out = U1T; Kd = 768;  Nd = 256;  bx = t & 7;  by = t >> 3; }
  else if (t < 1344) { t -= 576;  in = V1; out = V1T; Kd = 256;  Nd = 3072; bx = t % 96; by = t / 96; }
  else if (t < 2112) { t -= 1344; in = U2; out = U2T; Kd = 3072; Nd = 256;  bx = t & 7;  by = t >> 3; }
  else               { t -= 2112; in = V2; out = V2T; Kd = 256;  Nd = 768;  bx = t % 24; by = t / 24; }
  __shared__ bf16_t tl[32][33];
  const int X = bx * 32, Y = by * 32;
  const int x = threadIdx.x & 31, y = threadIdx.x >> 5;
  for (int i = 0; i < 32; i += 8)
    tl[y + i][x] = (bf16_t)loadf(in, (size_t)(Y + y + i) * Nd + X + x, isf);
  __syncthreads();
  for (int i = 0; i < 32; i += 8)
    out[(size_t)(X + y + i) * Kd + Y + x] = tl[x][y + i];
}

// ---------------------------------------------------------------------------
// repack V1T/U2T into swizzled, linearly-stageable chunk layouts for ffn_k.
// V1S[ch][dl][c*8+j] = V1T[ch*32+dl][(c^(dl&7))*8 + j]   (ch 0..95, c 0..31)
// U2S[ch][n][c*8+j]  = U2T[n][ch*32 + (c^(n&3))*8 + j]   (c 0..3)
// ---------------------------------------------------------------------------
__global__ __launch_bounds__(256) void swz_k(const bf16_t* __restrict__ V1T,
                                             const bf16_t* __restrict__ U2T,
                                             bf16_t* __restrict__ V1S,
                                             bf16_t* __restrict__ U2S) {
  const int u = blockIdx.x * 256 + threadIdx.x;
  if (u < 98304) {
    const int ch = u >> 10, dl = (u >> 5) & 31, c = u & 31;
    *(bf16x8*)(V1S + (size_t)u * 8) =
        *(const bf16x8*)(V1T + (size_t)(ch * 32 + dl) * 256 +
                         ((c ^ (dl & 7)) * 8));
  } else {
    const int u2 = u - 98304;
    const int ch = u2 >> 10, n = (u2 >> 2) & 255, c = u2 & 3;
    *(bf16x8*)(U2S + (size_t)u2 * 8) =
        *(const bf16x8*)(U2T + (size_t)n * 3072 + ch * 32 +
                         ((c ^ (n & 3)) * 8));
  }
}

// ---------------------------------------------------------------------------
// 128x128-tile GEMM. EPI 3: QKV scatter (+biases), Q pre-scaled, V transposed
// ---------------------------------------------------------------------------
template <int EPI>
__global__ __launch_bounds__(256, 3) void gemm_bt(
    const bf16_t* __restrict__ A, const bf16_t* __restrict__ Bt, int N, int K,
    int lda, int ldb, bf16_t* __restrict__ Qb, bf16_t* __restrict__ Kb,
    bf16_t* __restrict__ Vb, const bf16_t* __restrict__ bqkv) {
  __shared__ __attribute__((aligned(16))) bf16_t As[128 * 64];
  __shared__ __attribute__((aligned(16))) bf16_t Bs[128 * 64];
  const int tid = threadIdx.x;
  const int w = tid >> 6, l = tid & 63;
  const int quad = l >> 4, l15 = l & 15;
  const int m0 = blockIdx.y * 128, n0 = blockIdx.x * 128;

  const bf16_t* gA = A + (size_t)(m0 + w * 32 + (l >> 3)) * lda + (l & 7) * 8;
  const bf16_t* gB = Bt + (size_t)(n0 + w * 32 + (l >> 3)) * ldb + (l & 7) * 8;
  bf16_t* lA = &As[(w * 32) * 64];
  bf16_t* lB = &Bs[(w * 32) * 64];

  f32x4 acc[4][4] = {};
  const int wm = (w >> 1) * 64, wn = (w & 1) * 64;

  for (int k0 = 0; k0 < K; k0 += 64) {
    for (int c = 0; c < 4; ++c) {
      GLD_TO_LDS(gA + (size_t)(c * 8) * lda + k0, lA + (c * 8) * 64);
      GLD_TO_LDS(gB + (size_t)(c * 8) * ldb + k0, lB + (c * 8) * 64);
    }
    __syncthreads();
    for (int kk = 0; kk < 2; ++kk) {
      bf16x8 af[4], bfr[4];
      for (int i = 0; i < 4; ++i)
        af[i] = *(const bf16x8*)&As[(wm + i * 16 + l15) * 64 + kk * 32 + quad * 8];
      for (int i = 0; i < 4; ++i)
        bfr[i] = *(const bf16x8*)&Bs[(wn + i * 16 + l15) * 64 + kk * 32 + quad * 8];
      for (int mi = 0; mi < 4; ++mi)
        for (int ni = 0; ni < 4; ++ni)
          acc[mi][ni] = MFMA16(af[mi], bfr[ni], acc[mi][ni]);
    }
    __syncthreads();
  }

  for (int mi = 0; mi < 4; ++mi) {
    for (int ni = 0; ni < 4; ++ni) {
      const int gn = n0 + wn + ni * 16 + l15;
      const int s = gn / 768, rem = gn - s * 768;
      const int h = rem >> 6, e = rem & 63;
      const float bvv = (float)bqkv[gn];
      for (int r = 0; r < 4; ++r) {
        const int gm = m0 + wm + mi * 16 + quad * 4 + r;
        const int b_ = gm >> 11, mloc = gm & 2047;
        const int bh = b_ * 12 + h;
        float v = acc[mi][ni][r] + bvv;
        if (s == 0) {
          Qb[((size_t)bh * 2048 + mloc) * 64 + e] = (bf16_t)(v * QSCALE);
        } else if (s == 1) {
          Kb[((size_t)bh * 2048 + mloc) * 64 + e] = (bf16_t)v;
        } else {
          Vb[((size_t)bh * 64 + e) * 2048 + mloc] = (bf16_t)v;  // transposed
        }
      }
    }
  }
}

// ---------------------------------------------------------------------------
// 64x64-tile GEMM (skinny). EPI 0: bf16 store | 8: Cf = acc (fp32)
// ---------------------------------------------------------------------------
template <int EPI>
__global__ __launch_bounds__(256, 4) void gemm64(
    const bf16_t* __restrict__ A, const bf16_t* __restrict__ Bt, int N, int K,
    int lda, int ldb, bf16_t* __restrict__ Cb, float* __restrict__ Cf) {
  __shared__ __attribute__((aligned(16))) bf16_t As[64 * 64];
  __shared__ __attribute__((aligned(16))) bf16_t Bs[64 * 64];
  const int tid = threadIdx.x;
  const int w = tid >> 6, l = tid & 63;
  const int quad = l >> 4, l15 = l & 15;
  const int m0 = blockIdx.y * 64, n0 = blockIdx.x * 64;

  const bf16_t* gA = A + (size_t)(m0 + w * 16 + (l >> 3)) * lda + (l & 7) * 8;
  const bf16_t* gB = Bt + (size_t)(n0 + w * 16 + (l >> 3)) * ldb + (l & 7) * 8;
  bf16_t* lA = &As[(w * 16) * 64];
  bf16_t* lB = &Bs[(w * 16) * 64];

  f32x4 acc[4] = {};

  for (int k0 = 0; k0 < K; k0 += 64) {
    for (int c = 0; c < 2; ++c) {
      GLD_TO_LDS(gA + (size_t)(c * 8) * lda + k0, lA + (c * 8) * 64);
      GLD_TO_LDS(gB + (size_t)(c * 8) * ldb + k0, lB + (c * 8) * 64);
    }
    __syncthreads();
    for (int kk = 0; kk < 2; ++kk) {
      bf16x8 af = *(const bf16x8*)&As[(w * 16 + l15) * 64 + kk * 32 + quad * 8];
      bf16x8 bfr[4];
      for (int i = 0; i < 4; ++i)
        bfr[i] = *(const bf16x8*)&Bs[(i * 16 + l15) * 64 + kk * 32 + quad * 8];
      for (int ni = 0; ni < 4; ++ni) acc[ni] = MFMA16(af, bfr[ni], acc[ni]);
    }
    __syncthreads();
  }

  for (int ni = 0; ni < 4; ++ni) {
    const int gn = n0 + ni * 16 + l15;
    for (int r = 0; r < 4; ++r) {
      const int gm = m0 + w * 16 + quad * 4 + r;
      if (EPI == 0)
        Cb[(size_t)gm * N + gn] = (bf16_t)acc[ni][r];
      else
        Cf[(size_t)gm * N + gn] = acc[ni][r];
    }
  }
}

// ---------------------------------------------------------------------------
// Flash attention, 128-row Q tiles (32 q-rows/wave), grid (16,48).
// In-register P: QK^T C-layout (col=q, k=quad*4+r) IS the B-fragment of
// v_mfma 16x16x16 bf16, so exp2(S) feeds PV directly — no P LDS round-trip.
// Double-buffered K/V staging, counted vmcnt, raw barriers, setprio on MFMA.
// ---------------------------------------------------------------------------
__global__ __launch_bounds__(256, 3) void attn_k(const bf16_t* __restrict__ Qg,
                                                 const bf16_t* __restrict__ Kg,
                                                 const bf16_t* __restrict__ Vtg,
                                                 bf16_t* __restrict__ AO) {
  // [buf 0|1][ K(64x64) | V(64x64) ]  = 32 KB
  __shared__ __attribute__((aligned(16))) bf16_t KVf[2 * 2 * 64 * 64];
  const int tid = threadIdx.x, w = tid >> 6, l = tid & 63;
  const int quad = l >> 4, l15 = l & 15;
  const int bh = blockIdx.y;
  const int q0 = blockIdx.x * 128;
  const size_t base = (size_t)bh * 2048 * 64;

  bf16x8 Qf[2][2];
  for (int mi = 0; mi < 2; ++mi)
    for (int kk = 0; kk < 2; ++kk)
      Qf[mi][kk] = *(const bf16x8*)(Qg + base +
                                    (size_t)(q0 + w * 32 + mi * 16 + l15) * 64 +
                                    kk * 32 + quad * 8);

  f32x4 Oa[4][2] = {};
  float lrun[2] = {0.f, 0.f};

  const int lrow = l >> 3, lc = l & 7;
  const int csw = ((lc ^ (lrow & 7)) * 8);
  const bf16_t* kg0 = Kg + base + (size_t)(w * 8 + lrow) * 64 + csw;
  const bf16_t* kg1 = kg0 + 32 * 64;
  const bf16_t* vg0 = Vtg + ((size_t)bh * 64 + w * 8 + lrow) * 2048 + csw;
  const bf16_t* vg1 = vg0 + (size_t)32 * 2048;
  const int lofs = w * 512;

  // prologue: stage tile 0 into buf 0
  GLD_TO_LDS(kg0, KVf + lofs);
  GLD_TO_LDS(kg1, KVf + 2048 + lofs);
  GLD_TO_LDS(vg0, KVf + 4096 + lofs);
  GLD_TO_LDS(vg1, KVf + 6144 + lofs);
  kg0 += 4096; kg1 += 4096; vg0 += 64; vg1 += 64;

  for (int it = 0; it < 32; ++it) {
    bf16_t* Ks = KVf + (it & 1) * 8192;
    bf16_t* Vt = Ks + 4096;
    if (it < 31) {
      // prefetch tile it+1 into the other buffer; keep 4 loads in flight
      bf16_t* Kn = KVf + ((it + 1) & 1) * 8192;
      GLD_TO_LDS(kg0, Kn + lofs);
      GLD_TO_LDS(kg1, Kn + 2048 + lofs);
      GLD_TO_LDS(vg0, Kn + 4096 + lofs);
      GLD_TO_LDS(vg1, Kn + 6144 + lofs);
      kg0 += 4096; kg1 += 4096; vg0 += 64; vg1 += 64;
      asm volatile("s_waitcnt vmcnt(4)" ::: "memory");
    } else {
      asm volatile("s_waitcnt vmcnt(0)" ::: "memory");
    }
    __builtin_amdgcn_s_barrier();
    asm volatile("" ::: "memory");

    // QK^T: S[nr][mi] = K-rows x Q   (C: row=k, col=q)
    f32x4 S[4][2] = {};
    for (int kk = 0; kk < 2; ++kk) {
      bf16x8 af[4];
      for (int nr = 0; nr < 4; ++nr) {
        const int row = nr * 16 + l15, ch = kk * 4 + quad;
        af[nr] = *(const bf16x8*)&Ks[row * 64 + ((ch ^ (row & 7)) * 8)];
      }
      __builtin_amdgcn_s_setprio(1);
      for (int nr = 0; nr < 4; ++nr)
        for (int mi = 0; mi < 2; ++mi)
          S[nr][mi] = MFMA16(af[nr], Qf[mi][kk], S[nr][mi]);
      __builtin_amdgcn_s_setprio(0);
    }

    // no-max softmax, entirely in registers: pexp[nr][mi] is directly the
    // B-fragment (col=l15=q, k=quad*4+j) of the K=16 PV MFMA.
    bf16x4 pexp[4][2];
    for (int nr = 0; nr < 4; ++nr)
      for (int mi = 0; mi < 2; ++mi) {
        float ps = 0.f;
        bf16x4 pk;
        for (int r = 0; r < 4; ++r) {
          const float p = exp2f(S[nr][mi][r]);
          ps += p;
          pk[r] = (bf16_t)p;
        }
        pexp[nr][mi] = pk;
        lrun[mi] += ps;
      }

    // PV: Oa[ei][mi] += V^T fragment (A: row=e, k=quad*4+j) x pexp
    __builtin_amdgcn_s_setprio(1);
    for (int ei = 0; ei < 4; ++ei) {
      const int row = ei * 16 + l15, rsw = row & 7;
      for (int nr = 0; nr < 4; ++nr) {
        const int ch = nr * 2 + (quad >> 1);
        bf16x4 vfr = *(const bf16x4*)&Vt[row * 64 + ((ch ^ rsw) * 8) +
                                         (quad & 1) * 4];
        Oa[ei][0] = MFMA16K16(vfr, pexp[nr][0], Oa[ei][0]);
        Oa[ei][1] = MFMA16K16(vfr, pexp[nr][1], Oa[ei][1]);
      }
    }
    __builtin_amdgcn_s_setprio(0);
    asm volatile("s_waitcnt lgkmcnt(0)" ::: "memory");
    __builtin_amdgcn_s_barrier();
    asm volatile("" ::: "memory");
  }

  for (int mi = 0; mi < 2; ++mi) {
    lrun[mi] += __shfl_xor(lrun[mi], 16);
    lrun[mi] += __shfl_xor(lrun[mi], 32);
  }

  // epilogue: O^T -> token rows via LDS (128x64), coalesced write
  bf16_t* Os = KVf;
  const float inv0 = 1.f / lrun[0], inv1 = 1.f / lrun[1];
  for (int mi = 0; mi < 2; ++mi) {
    const float inv = mi ? inv1 : inv0;
    const int mrow = w * 32 + mi * 16 + l15;
    for (int ei = 0; ei < 4; ++ei) {
      const int e0 = ei * 16 + quad * 4;
      const int ch = e0 >> 3, e7 = e0 & 7;
      bf16x4 q;
      q[0] = (bf16_t)(Oa[ei][mi][0] * inv);
      q[1] = (bf16_t)(Oa[ei][mi][1] * inv);
      q[2] = (bf16_t)(Oa[ei][mi][2] * inv);
      q[3] = (bf16_t)(Oa[ei][mi][3] * inv);
      *(bf16x4*)&Os[mrow * 64 + ((ch ^ (mrow & 7)) * 8) + e7] = q;
    }
  }
  __syncthreads();
  const int b_ = bh / 12, h_ = bh % 12;
  const int row = tid >> 1;
  for (int c = 0; c < 4; ++c) {
    const int ch = (tid & 1) * 4 + c;
    bf16x8 d = *(const bf16x8*)&Os[row * 64 + ((ch ^ (row & 7)) * 8)];
    *(bf16x8*)(AO + ((size_t)(b_ * 2048 + q0 + row)) * 768 + h_ * 64 + ch * 8) = d;
  }
}

// ---------------------------------------------------------------------------
// Fused FFN middle: per block (64 tokens, dff group g of 768):
//   loop 24 chunks of 32 dff: Ht = V1c(A) x mid(B) -> +b1, gelu -> LDS ->
//   acc[tok][256] += H x U2c.  acc stays in registers; write bf16 slice.
// Double-buffered V1/U2 staging with counted vmcnt + raw barriers.
// ---------------------------------------------------------------------------
__global__ __launch_bounds__(256, 2) void ffn_k(const bf16_t* __restrict__ mid,
                                                const bf16_t* __restrict__ V1S,
                                                const bf16_t* __restrict__ U2S,
                                                const bf16_t* __restrict__ b1c,
                                                bf16_t* __restrict__ T2s) {
  __shared__ __attribute__((aligned(16))) bf16_t V1l[2][32 * 256];
  __shared__ __attribute__((aligned(16))) bf16_t U2l[2][256 * 32];
  __shared__ __attribute__((aligned(16))) bf16_t Hl[4][16 * 32];
  __shared__ __attribute__((aligned(16))) bf16_t Bl[768];
  const int tid = threadIdx.x, w = tid >> 6, l = tid & 63;
  const int quad = l >> 4, l15 = l & 15;
  const int m0 = blockIdx.x * 64;
  const int g = blockIdx.y;

  if (tid < 96)
    *(bf16x8*)&Bl[tid * 8] = *(const bf16x8*)(b1c + g * 768 + tid * 8);

  bf16x8 mf[8];
  for (int kk = 0; kk < 8; ++kk)
    mf[kk] = *(const bf16x8*)(mid + (size_t)(m0 + w * 16 + l15) * 256 +
                              kk * 32 + quad * 8);

  f32x4 acc[16] = {};

  const bf16_t* vs = V1S + (size_t)g * 24 * 8192 + w * 512 + l * 8;
  const bf16_t* us = U2S + (size_t)g * 24 * 8192 + w * 512 + l * 8;
  const int lofs = w * 512;

  // prologue: stage chunk 0 into buf 0
  for (int i = 0; i < 4; ++i) {
    GLD_TO_LDS(vs + i * 2048, V1l[0] + lofs + i * 2048);
    GLD_TO_LDS(us + i * 2048, U2l[0] + lofs + i * 2048);
  }
  vs += 8192; us += 8192;

  for (int c = 0; c < 24; ++c) {
    const int cb = c & 1;
    if (c < 23) {
      // prefetch chunk c+1 into the other buffer; keep 8 loads in flight
      for (int i = 0; i < 4; ++i) {
        GLD_TO_LDS(vs + i * 2048, V1l[cb ^ 1] + lofs + i * 2048);
        GLD_TO_LDS(us + i * 2048, U2l[cb ^ 1] + lofs + i * 2048);
      }
      vs += 8192; us += 8192;
      asm volatile("s_waitcnt vmcnt(8)" ::: "memory");
    } else {
      asm volatile("s_waitcnt vmcnt(0)" ::: "memory");
    }
    __builtin_amdgcn_s_barrier();
    asm volatile("" ::: "memory");

    // GEMM1: Ht[d][tok]
    f32x4 S[2] = {};
    for (int kk = 0; kk < 8; ++kk) {
      const int ck = kk * 4 + quad;
      bf16x8 a0 = *(const bf16x8*)&V1l[cb][l15 * 256 + ((ck ^ (l15 & 7)) * 8)];
      bf16x8 a1 =
          *(const bf16x8*)&V1l[cb][(16 + l15) * 256 + ((ck ^ (l15 & 7)) * 8)];
      __builtin_amdgcn_s_setprio(1);
      S[0] = MFMA16(a0, mf[kk], S[0]);
      S[1] = MFMA16(a1, mf[kk], S[1]);
      __builtin_amdgcn_s_setprio(0);
    }
    // bias + gelu, pack into Hl[tok][dff]
    for (int mt = 0; mt < 2; ++mt) {
      bf16x4 bb = *(const bf16x4*)&Bl[c * 32 + mt * 16 + quad * 4];
      bf16x4 hv;
      for (int r = 0; r < 4; ++r) {
        const float v = S[mt][r] + (float)bb[r];
        const float z2 = 2.302589f * (v + 0.044715f * v * v * v);
        hv[r] = (bf16_t)(v / (1.f + exp2f(-z2)));
      }
      const int hch = mt * 2 + (quad >> 1);
      *(bf16x4*)&Hl[w][l15 * 32 + ((hch ^ (l15 & 3)) * 8) + (quad & 1) * 4] = hv;
    }
    asm volatile("s_waitcnt lgkmcnt(0)" ::: "memory");

    // GEMM2: acc[tok][n] += H x U2c
    bf16x8 pa = *(const bf16x8*)&Hl[w][l15 * 32 + ((quad ^ (l15 & 3)) * 8)];
    __builtin_amdgcn_s_setprio(1);
    for (int ni = 0; ni < 16; ++ni) {
      const int n = ni * 16 + l15;
      bf16x8 bfr = *(const bf16x8*)&U2l[cb][n * 32 + ((quad ^ (n & 3)) * 8)];
      acc[ni] = MFMA16(pa, bfr, acc[ni]);
    }
    __builtin_amdgcn_s_setprio(0);
    asm volatile("s_waitcnt lgkmcnt(0)" ::: "memory");
    __builtin_amdgcn_s_barrier();
    asm volatile("" ::: "memory");
  }

  bf16_t* outp = T2s + ((size_t)g * 8192 + m0 + w * 16 + quad * 4) * 256;
  for (int ni = 0; ni < 16; ++ni)
    for (int r = 0; r < 4; ++r)
      outp[(size_t)r * 256 + ni * 16 + l15] = (bf16_t)acc[ni][r];
}

// sum 4 bf16 slices -> bf16
__global__ __launch_bounds__(256) void sum4_k(const bf16_t* __restrict__ T2s,
                                              bf16_t* __restrict__ out) {
  const size_t i = ((size_t)blockIdx.x * 256 + threadIdx.x) * 4;
  f32x4 s = {};
  for (int g = 0; g < 4; ++g) {
    bf16x4 v = *(const bf16x4*)(T2s + (size_t)g * 2097152 + i);
    for (int r = 0; r < 4; ++r) s[r] += (float)v[r];
  }
  bf16x4 o;
  for (int r = 0; r < 4; ++r) o[r] = (bf16_t)s[r];
  *(bf16x4*)(out + i) = o;
}

// ---------------------------------------------------------------------------
// Fused residual + bias + LayerNorm.
// ---------------------------------------------------------------------------
__global__ __launch_bounds__(256) void lnf_k(
    const float* __restrict__ Acc, const void* __restrict__ resid,
    const int* __restrict__ rflag, const bf16_t* __restrict__ bias,
    const bf16_t* __restrict__ g, const bf16_t* __restrict__ b, void* out,
    const int* __restrict__ oflag) {
  const int wv = threadIdx.x >> 6, l = threadIdx.x & 63;
  const int row = blockIdx.x * 4 + wv;
  const int risf = rflag ? *rflag : 0;
  const int f32out = oflag ? *oflag : 0;
  float v[12], s = 0.f, s2 = 0.f;
  for (int j = 0; j < 3; ++j) {
    const int c0 = j * 256 + l * 4;
    const f32x4 a = *(const f32x4*)(Acc + (size_t)row * 768 + c0);
    for (int r = 0; r < 4; ++r) {
      const float f = a[r] + (float)bias[c0 + r] +
                      loadf(resid, (size_t)row * 768 + c0 + r, risf);
      v[j * 4 + r] = f;
      s += f;
      s2 += f * f;
    }
  }
  for (int m = 32; m; m >>= 1) {
    s += __shfl_xor(s, m);
    s2 += __shfl_xor(s2, m);
  }
  const float mu = s * (1.f / 768.f);
  const float var = s2 * (1.f / 768.f) - mu * mu;
  const float rs = rsqrtf(var + 1e-5f);
  for (int j = 0; j < 3; ++j) {
    const int c0 = j * 256 + l * 4;
    if (f32out) {
      f32x4 o;
      for (int r = 0; r < 4; ++r)
        o[r] = (v[j * 4 + r] - mu) * rs * (float)g[c0 + r] + (float)b[c0 + r];
      *(f32x4*)((float*)out + (size_t)row * 768 + c0) = o;
    } else {
      bf16x4 o;
      for (int r = 0; r < 4; ++r)
        o[r] = (bf16_t)((v[j * 4 + r] - mu) * rs * (float)g[c0 + r] +
                        (float)b[c0 + r]);
      *(bf16x4*)((bf16_t*)out + (size_t)row * 768 + c0) = o;
    }
  }
}

// ---------------------------------------------------------------------------
extern "C" void kernel_launch(void* const* d_in, const int* in_sizes, int n_in,
                              void* d_out, int out_size, void* d_ws,
                              size_t ws_size, hipStream_t stream) {
  const void* x   = d_in[0];
  const void* Pq  = d_in[2];
  const void* Vq  = d_in[3];
  const void* bq  = d_in[4];
  const void* Pk  = d_in[5];
  const void* Vk  = d_in[6];
  const void* bk  = d_in[7];
  const void* Pv  = d_in[8];
  const void* Vv  = d_in[9];
  const void* bv  = d_in[10];
  const void* Uo  = d_in[11];
  const void* Vo  = d_in[12];
  const void* bo  = d_in[13];
  const void* U1  = d_in[14];
  const void* V1  = d_in[15];
  const void* b1  = d_in[16];
  const void* U2  = d_in[17];
  const void* V2  = d_in[18];
  const void* b2  = d_in[19];
  const void* g1  = d_in[20];
  const void* be1 = d_in[21];
  const void* g2  = d_in[22];
  const void* be2 = d_in[23];

  // ---- workspace layout, peak 60,182,528 B ----
  char* ws = (char*)d_ws;
  bf16_t* WtQKV = (bf16_t*)(ws + 0);
  bf16_t* UoT   = (bf16_t*)(ws + 3538944);
  bf16_t* VoT   = (bf16_t*)(ws + 3932160);
  bf16_t* U1T   = (bf16_t*)(ws + 4325376);
  bf16_t* V1T   = (bf16_t*)(ws + 4718592);
  bf16_t* U2T   = (bf16_t*)(ws + 6291456);
  bf16_t* V2T   = (bf16_t*)(ws + 7864320);
  bf16_t* Bc    = (bf16_t*)(ws + 8257536);
  int*    flag  = (int*)(ws + 8277504);
  bf16_t* xc    = (bf16_t*)(ws + 8278016);    // 12.58 MB
  bf16_t* Qb    = (bf16_t*)(ws + 20860928);   // 12.58 MB
  bf16_t* Kb    = (bf16_t*)(ws + 33443840);   // 12.58 MB
  bf16_t* Vb    = (bf16_t*)(ws + 46026752);   // -> 58,609,664
  bf16_t* WoT   = (bf16_t*)(ws + 58609664);   // -> 59,789,312
  bf16_t* Uo_c  = (bf16_t*)(ws + 59789312);   // -> 60,182,528
  // aliases (after attention, Qb/Kb/Vb dead):
  bf16_t* AO   = xc;                           // attn out over dead xc
  bf16_t* X1   = AO;                           // LN1 out in place
  bf16_t* T    = Qb;                           // mid / t2 bf16 4.2 MB
  bf16_t* T2s  = (bf16_t*)(ws + 25055232);    // 4 x 4.19 MB -> 41,832,448
  bf16_t* V1S  = (bf16_t*)(ws + 41832448);    // 1.5 MB
  bf16_t* U2S  = (bf16_t*)(ws + 43405312);    // 1.5 MB -> 44,978,176
  float*  Rf   = (float*)(ws + 33443840);     // fp32 25.2 MB (Kb+Vb slots)

  bf16_t* bqkvc = Bc + 0;
  bf16_t* boc   = Bc + 2304;
  bf16_t* b1c   = Bc + 3072;
  bf16_t* b2c   = Bc + 6144;
  bf16_t* g1c   = Bc + 6912;
  bf16_t* be1c  = Bc + 7680;
  bf16_t* g2c   = Bc + 8448;
  bf16_t* be2c  = Bc + 9216;

  // ---- dtype detection + canonicalization + weight prep ----
  detect_k<<<1, 256, 0, stream>>>((const unsigned short*)x, flag);
  cvtin_k<<<4096, 256, 0, stream>>>(x, xc, 8192 * 768, flag);
  cvtin_k<<<768, 256, 0, stream>>>(Uo, Uo_c, 768 * 256, flag);
  bcat_k<<<39, 256, 0, stream>>>(bq, bk, bv, bo, b1, b2, g1, be1, g2, be2, Bc,
                                 flag);
  wqkv_k<<<36, 256, 0, stream>>>(Pq, Vq, Pk, Vk, Pv, Vv, WtQKV, flag);
  transpose_all_k<<<2304, 256, 0, stream>>>(Uo, Vo, U1, V1, U2, V2, UoT, VoT,
                                            U1T, V1T, U2T, V2T, flag);
  gemm64<0><<<dim3(12, 12), 256, 0, stream>>>(VoT, Uo_c, 768, 256, 256, 256,
                                              WoT, nullptr);

  // ---- QKV projection (Q pre-scaled) ----
  gemm_bt<3><<<dim3(18, 64), 256, 0, stream>>>(xc, WtQKV, 2304, 768, 768, 768,
                                               Qb, Kb, Vb, bqkvc);

  // ---- flash attention -> AO ----
  attn_k<<<dim3(16, 48), 256, 0, stream>>>(Qb, Kb, Vb, AO);

  // ---- output projection: Rf = AO@WoT; X1 = LN(x + Rf + bo) ----
  gemm64<8><<<dim3(12, 128), 256, 0, stream>>>(AO, WoT, 768, 768, 768, 768,
                                               nullptr, Rf);
  lnf_k<<<2048, 256, 0, stream>>>(Rf, x, flag, boc, g1c, be1c, X1, nullptr);

  // ---- FFN: mid = X1@U1; fused gelu+U2 contraction; t2@V2; LN2 ----
  swz_k<<<768, 256, 0, stream>>>(V1T, U2T, V1S, U2S);
  gemm64<0><<<dim3(4, 128), 256, 0, stream>>>(X1, U1T, 256, 768, 768, 768, T,
                                              nullptr);
  ffn_k<<<dim3(128, 4), 256, 0, stream>>>(T, V1S, U2S, b1c, T2s);
  sum4_k<<<2048, 256, 0, stream>>>(T2s, T);
  gemm64<8><<<dim3(12, 128), 256, 0, stream>>>(T, V2T, 768, 256, 256, 256,
                                               nullptr, Rf);
  lnf_k<<<2048, 256, 0, stream>>>(Rf, X1, nullptr, b2c, g2c, be2c, d_out, flag);
}

// Round 4
// 503.584 us; speedup vs baseline: 1.0333x; 1.0333x over previous
//
#include <hip/hip_runtime.h>
#include <cmath>

typedef __bf16 bf16_t;
typedef bf16_t bf16x8 __attribute__((ext_vector_type(8)));
typedef bf16_t bf16x4 __attribute__((ext_vector_type(4)));
typedef float f32x4 __attribute__((ext_vector_type(4)));

#define MFMA16(a, b, c) __builtin_amdgcn_mfma_f32_16x16x32_bf16(a, b, c, 0, 0, 0)
#define GLD_TO_LDS(gp, lp)                                                        \
  __builtin_amdgcn_global_load_lds(                                               \
      (const __attribute__((address_space(1))) void*)(gp),                        \
      (__attribute__((address_space(3))) void*)(lp), 16, 0, 0)

__device__ __forceinline__ float loadf(const void* p, size_t i, int isf) {
  return isf ? ((const float*)p)[i] : (float)((const bf16_t*)p)[i];
}

// softmax scale folded into Q: 1/sqrt(64) * log2(e)
#define QSCALE 0.18033688f

// ---------------------------------------------------------------------------
__global__ __launch_bounds__(256) void detect_k(
    const unsigned short* __restrict__ xr, int* __restrict__ flag) {
  __shared__ int s;
  if (threadIdx.x == 0) s = 0;
  __syncthreads();
  int bad = 0;
  for (int i = 0; i < 32; ++i) {
    const unsigned short u = xr[threadIdx.x * 32 + i];
    const int e = (u >> 7) & 0xFF;
    if (e >= 0xC8) bad = 1;
  }
  if (bad) atomicOr(&s, 1);
  __syncthreads();
  if (threadIdx.x == 0) *flag = s;
}

__global__ __launch_bounds__(256) void cvtin_k(const void* __restrict__ src,
                                               bf16_t* __restrict__ dst, int n,
                                               const int* __restrict__ flagp) {
  const int isf = *flagp;
  for (int i = blockIdx.x * 256 + threadIdx.x; i < n; i += gridDim.x * 256)
    dst[i] = (bf16_t)loadf(src, i, isf);
}

__global__ __launch_bounds__(256) void bcat_k(
    const void* bq, const void* bk, const void* bv, const void* bo,
    const void* b1, const void* b2, const void* g1, const void* be1,
    const void* g2, const void* be2, bf16_t* __restrict__ dst,
    const int* __restrict__ flagp) {
  const int isf = *flagp;
  const int i = blockIdx.x * 256 + threadIdx.x;
  if (i >= 9984) return;
  const void* src;
  int off;
  if (i < 768)       { src = bq;  off = i; }
  else if (i < 1536) { src = bk;  off = i - 768; }
  else if (i < 2304) { src = bv;  off = i - 1536; }
  else if (i < 3072) { src = bo;  off = i - 2304; }
  else if (i < 6144) { src = b1;  off = i - 3072; }
  else if (i < 6912) { src = b2;  off = i - 6144; }
  else if (i < 7680) { src = g1;  off = i - 6912; }
  else if (i < 8448) { src = be1; off = i - 7680; }
  else if (i < 9216) { src = g2;  off = i - 8448; }
  else               { src = be2; off = i - 9216; }
  dst[i] = (bf16_t)loadf(src, off, isf);
}

// ---------------------------------------------------------------------------
__global__ __launch_bounds__(256) void wqkv_k(
    const void* __restrict__ Pq, const void* __restrict__ Vq,
    const void* __restrict__ Pk, const void* __restrict__ Vk,
    const void* __restrict__ Pv, const void* __restrict__ Vv,
    bf16_t* __restrict__ Wt, const int* __restrict__ flagp) {
  const int isf = *flagp;
  const int sh = blockIdx.x, s = sh / 12, h = sh % 12;
  const void* P = (s == 0) ? Pq : (s == 1) ? Pk : Pv;
  const void* Vm = (s == 0) ? Vq : (s == 1) ? Vk : Vv;
  __shared__ float Vl[32 * 64];
  const int tid = threadIdx.x;
  for (int i = tid; i < 2048; i += 256)
    Vl[i] = loadf(Vm, (size_t)h * 2048 + i, isf);
  __syncthreads();
  for (int kb = 0; kb < 3; ++kb) {
    const int k = kb * 256 + tid;
    float pr[32];
    const size_t prow = ((size_t)h * 768 + k) * 32;
    for (int r = 0; r < 32; ++r) pr[r] = loadf(P, prow + r, isf);
    for (int e = 0; e < 64; ++e) {
      float a = 0.f;
      for (int r = 0; r < 32; ++r) a += pr[r] * Vl[r * 64 + e];
      Wt[((size_t)sh * 64 + e) * 768 + k] = (bf16_t)a;
    }
  }
}

// ---------------------------------------------------------------------------
__global__ __launch_bounds__(256) void transpose_all_k(
    const void* Uo, const void* Vo, const void* U1, const void* V1,
    const void* U2, const void* V2, bf16_t* UoT, bf16_t* VoT, bf16_t* U1T,
    bf16_t* V1T, bf16_t* U2T, bf16_t* V2T, const int* __restrict__ flagp) {
  const int isf = *flagp;
  int t = blockIdx.x;
  const void* in;
  bf16_t* out;
  int Kd, Nd, bx, by;
  if (t < 192)       { in = Uo; out = UoT; Kd = 768;  Nd = 256;  bx = t & 7;  by = t >> 3; }
  else if (t < 384)  { t -= 192;  in = Vo; out = VoT; Kd = 256;  Nd = 768;  bx = t % 24; by = t / 24; }
  else if (t < 576)  { t -= 384;  in = U1; out = U1T; Kd = 768;  Nd = 256;  bx = t & 7;  by = t >> 3; }
  else if (t < 1344) { t -= 576;  in = V1; out = V1T; Kd = 256;  Nd = 3072; bx = t % 96; by = t / 96; }
  else if (t < 2112) { t -= 1344; in = U2; out = U2T; Kd = 3072; Nd = 256;  bx = t & 7;  by = t >> 3; }
  else               { t -= 2112; in = V2; out = V2T; Kd = 256;  Nd = 768;  bx = t % 24; by = t / 24; }
  __shared__ bf16_t tl[32][33];
  const int X = bx * 32, Y = by * 32;
  const int x = threadIdx.x & 31, y = threadIdx.x >> 5;
  for (int i = 0; i < 32; i += 8)
    tl[y + i][x] = (bf16_t)loadf(in, (size_t)(Y + y + i) * Nd + X + x, isf);
  __syncthreads();
  for (int i = 0; i < 32; i += 8)
    out[(size_t)(X + y + i) * Kd + Y + x] = tl[x][y + i];
}

// ---------------------------------------------------------------------------
// repack V1T/U2T into swizzled, linearly-stageable chunk layouts for ffn_k.
// V1S[ch][dl][c*8+j] = V1T[ch*32+dl][(c^(dl&7))*8 + j]   (ch 0..95, c 0..31)
// U2S[ch][n][c*8+j]  = U2T[n][ch*32 + (c^(n&3))*8 + j]   (c 0..3)
// ---------------------------------------------------------------------------
__global__ __launch_bounds__(256) void swz_k(const bf16_t* __restrict__ V1T,
                                             const bf16_t* __restrict__ U2T,
                                             bf16_t* __restrict__ V1S,
                                             bf16_t* __restrict__ U2S) {
  const int u = blockIdx.x * 256 + threadIdx.x;
  if (u < 98304) {
    const int ch = u >> 10, dl = (u >> 5) & 31, c = u & 31;
    *(bf16x8*)(V1S + (size_t)u * 8) =
        *(const bf16x8*)(V1T + (size_t)(ch * 32 + dl) * 256 +
                         ((c ^ (dl & 7)) * 8));
  } else {
    const int u2 = u - 98304;
    const int ch = u2 >> 10, n = (u2 >> 2) & 255, c = u2 & 3;
    *(bf16x8*)(U2S + (size_t)u2 * 8) =
        *(const bf16x8*)(U2T + (size_t)n * 3072 + ch * 32 +
                         ((c ^ (n & 3)) * 8));
  }
}

// ---------------------------------------------------------------------------
// 128x128-tile GEMM. EPI 3: QKV scatter (+biases), Q pre-scaled, V transposed
// ---------------------------------------------------------------------------
template <int EPI>
__global__ __launch_bounds__(256, 3) void gemm_bt(
    const bf16_t* __restrict__ A, const bf16_t* __restrict__ Bt, int N, int K,
    int lda, int ldb, bf16_t* __restrict__ Qb, bf16_t* __restrict__ Kb,
    bf16_t* __restrict__ Vb, const bf16_t* __restrict__ bqkv) {
  __shared__ __attribute__((aligned(16))) bf16_t As[128 * 64];
  __shared__ __attribute__((aligned(16))) bf16_t Bs[128 * 64];
  const int tid = threadIdx.x;
  const int w = tid >> 6, l = tid & 63;
  const int quad = l >> 4, l15 = l & 15;
  const int m0 = blockIdx.y * 128, n0 = blockIdx.x * 128;

  const bf16_t* gA = A + (size_t)(m0 + w * 32 + (l >> 3)) * lda + (l & 7) * 8;
  const bf16_t* gB = Bt + (size_t)(n0 + w * 32 + (l >> 3)) * ldb + (l & 7) * 8;
  bf16_t* lA = &As[(w * 32) * 64];
  bf16_t* lB = &Bs[(w * 32) * 64];

  f32x4 acc[4][4] = {};
  const int wm = (w >> 1) * 64, wn = (w & 1) * 64;

  for (int k0 = 0; k0 < K; k0 += 64) {
    for (int c = 0; c < 4; ++c) {
      GLD_TO_LDS(gA + (size_t)(c * 8) * lda + k0, lA + (c * 8) * 64);
      GLD_TO_LDS(gB + (size_t)(c * 8) * ldb + k0, lB + (c * 8) * 64);
    }
    __syncthreads();
    for (int kk = 0; kk < 2; ++kk) {
      bf16x8 af[4], bfr[4];
      for (int i = 0; i < 4; ++i)
        af[i] = *(const bf16x8*)&As[(wm + i * 16 + l15) * 64 + kk * 32 + quad * 8];
      for (int i = 0; i < 4; ++i)
        bfr[i] = *(const bf16x8*)&Bs[(wn + i * 16 + l15) * 64 + kk * 32 + quad * 8];
      for (int mi = 0; mi < 4; ++mi)
        for (int ni = 0; ni < 4; ++ni)
          acc[mi][ni] = MFMA16(af[mi], bfr[ni], acc[mi][ni]);
    }
    __syncthreads();
  }

  for (int mi = 0; mi < 4; ++mi) {
    for (int ni = 0; ni < 4; ++ni) {
      const int gn = n0 + wn + ni * 16 + l15;
      const int s = gn / 768, rem = gn - s * 768;
      const int h = rem >> 6, e = rem & 63;
      const float bvv = (float)bqkv[gn];
      for (int r = 0; r < 4; ++r) {
        const int gm = m0 + wm + mi * 16 + quad * 4 + r;
        const int b_ = gm >> 11, mloc = gm & 2047;
        const int bh = b_ * 12 + h;
        float v = acc[mi][ni][r] + bvv;
        if (s == 0) {
          Qb[((size_t)bh * 2048 + mloc) * 64 + e] = (bf16_t)(v * QSCALE);
        } else if (s == 1) {
          Kb[((size_t)bh * 2048 + mloc) * 64 + e] = (bf16_t)v;
        } else {
          Vb[((size_t)bh * 64 + e) * 2048 + mloc] = (bf16_t)v;  // transposed
        }
      }
    }
  }
}

// ---------------------------------------------------------------------------
// 64x64-tile GEMM (skinny). EPI 0: bf16 store | 8: Cf = acc (fp32)
// ---------------------------------------------------------------------------
template <int EPI>
__global__ __launch_bounds__(256, 4) void gemm64(
    const bf16_t* __restrict__ A, const bf16_t* __restrict__ Bt, int N, int K,
    int lda, int ldb, bf16_t* __restrict__ Cb, float* __restrict__ Cf) {
  __shared__ __attribute__((aligned(16))) bf16_t As[64 * 64];
  __shared__ __attribute__((aligned(16))) bf16_t Bs[64 * 64];
  const int tid = threadIdx.x;
  const int w = tid >> 6, l = tid & 63;
  const int quad = l >> 4, l15 = l & 15;
  const int m0 = blockIdx.y * 64, n0 = blockIdx.x * 64;

  const bf16_t* gA = A + (size_t)(m0 + w * 16 + (l >> 3)) * lda + (l & 7) * 8;
  const bf16_t* gB = Bt + (size_t)(n0 + w * 16 + (l >> 3)) * ldb + (l & 7) * 8;
  bf16_t* lA = &As[(w * 16) * 64];
  bf16_t* lB = &Bs[(w * 16) * 64];

  f32x4 acc[4] = {};

  for (int k0 = 0; k0 < K; k0 += 64) {
    for (int c = 0; c < 2; ++c) {
      GLD_TO_LDS(gA + (size_t)(c * 8) * lda + k0, lA + (c * 8) * 64);
      GLD_TO_LDS(gB + (size_t)(c * 8) * ldb + k0, lB + (c * 8) * 64);
    }
    __syncthreads();
    for (int kk = 0; kk < 2; ++kk) {
      bf16x8 af = *(const bf16x8*)&As[(w * 16 + l15) * 64 + kk * 32 + quad * 8];
      bf16x8 bfr[4];
      for (int i = 0; i < 4; ++i)
        bfr[i] = *(const bf16x8*)&Bs[(i * 16 + l15) * 64 + kk * 32 + quad * 8];
      for (int ni = 0; ni < 4; ++ni) acc[ni] = MFMA16(af, bfr[ni], acc[ni]);
    }
    __syncthreads();
  }

  for (int ni = 0; ni < 4; ++ni) {
    const int gn = n0 + ni * 16 + l15;
    for (int r = 0; r < 4; ++r) {
      const int gm = m0 + w * 16 + quad * 4 + r;
      if (EPI == 0)
        Cb[(size_t)gm * N + gn] = (bf16_t)acc[ni][r];
      else
        Cf[(size_t)gm * N + gn] = acc[ni][r];
    }
  }
}

// ---------------------------------------------------------------------------
// 128x64-tile GEMM for tall-skinny shapes (M large). 4 waves = 2M x 2N of
// 64x32 each; 16 MFMA/wave/K-step (2x gemm64 density). EPI 0/8 as gemm64.
// ---------------------------------------------------------------------------
template <int EPI>
__global__ __launch_bounds__(256, 3) void gemm128x64(
    const bf16_t* __restrict__ A, const bf16_t* __restrict__ Bt, int N, int K,
    int lda, int ldb, bf16_t* __restrict__ Cb, float* __restrict__ Cf) {
  __shared__ __attribute__((aligned(16))) bf16_t As[128 * 64];
  __shared__ __attribute__((aligned(16))) bf16_t Bs[64 * 64];
  const int tid = threadIdx.x;
  const int w = tid >> 6, l = tid & 63;
  const int quad = l >> 4, l15 = l & 15;
  const int m0 = blockIdx.y * 128, n0 = blockIdx.x * 64;

  const bf16_t* gA = A + (size_t)(m0 + w * 32 + (l >> 3)) * lda + (l & 7) * 8;
  const bf16_t* gB = Bt + (size_t)(n0 + w * 16 + (l >> 3)) * ldb + (l & 7) * 8;
  bf16_t* lA = &As[(w * 32) * 64];
  bf16_t* lB = &Bs[(w * 16) * 64];

  f32x4 acc[4][2] = {};
  const int wm = (w >> 1) * 64, wn = (w & 1) * 32;

  for (int k0 = 0; k0 < K; k0 += 64) {
    for (int c = 0; c < 4; ++c)
      GLD_TO_LDS(gA + (size_t)(c * 8) * lda + k0, lA + (c * 8) * 64);
    for (int c = 0; c < 2; ++c)
      GLD_TO_LDS(gB + (size_t)(c * 8) * ldb + k0, lB + (c * 8) * 64);
    __syncthreads();
    for (int kk = 0; kk < 2; ++kk) {
      bf16x8 af[4], bfr[2];
      for (int i = 0; i < 4; ++i)
        af[i] = *(const bf16x8*)&As[(wm + i * 16 + l15) * 64 + kk * 32 + quad * 8];
      for (int i = 0; i < 2; ++i)
        bfr[i] = *(const bf16x8*)&Bs[(wn + i * 16 + l15) * 64 + kk * 32 + quad * 8];
      for (int mi = 0; mi < 4; ++mi)
        for (int ni = 0; ni < 2; ++ni)
          acc[mi][ni] = MFMA16(af[mi], bfr[ni], acc[mi][ni]);
    }
    __syncthreads();
  }

  for (int mi = 0; mi < 4; ++mi) {
    for (int ni = 0; ni < 2; ++ni) {
      const int gn = n0 + wn + ni * 16 + l15;
      for (int r = 0; r < 4; ++r) {
        const int gm = m0 + wm + mi * 16 + quad * 4 + r;
        if (EPI == 0)
          Cb[(size_t)gm * N + gn] = (bf16_t)acc[mi][ni][r];
        else
          Cf[(size_t)gm * N + gn] = acc[mi][ni][r];
      }
    }
  }
}

// ---------------------------------------------------------------------------
// Flash attention, 128-row Q tiles (32 q-rows/wave), grid (16,48).
// Double-buffered K/V staging with counted vmcnt (never drains to 0 in the
// steady state); raw s_barrier; s_setprio around MFMA clusters.
// ---------------------------------------------------------------------------
__global__ __launch_bounds__(256, 3) void attn_k(const bf16_t* __restrict__ Qg,
                                                 const bf16_t* __restrict__ Kg,
                                                 const bf16_t* __restrict__ Vtg,
                                                 bf16_t* __restrict__ AO) {
  // [buf 0|1][ K(64x64) | V(64x64) ]  = 32 KB
  __shared__ __attribute__((aligned(16))) bf16_t KVf[2 * 2 * 64 * 64];
  __shared__ __attribute__((aligned(16))) bf16_t Pwf[4 * 32 * 64];
  const int tid = threadIdx.x, w = tid >> 6, l = tid & 63;
  const int quad = l >> 4, l15 = l & 15;
  bf16_t* Pw = Pwf + w * 32 * 64;
  const int bh = blockIdx.y;
  const int q0 = blockIdx.x * 128;
  const size_t base = (size_t)bh * 2048 * 64;

  bf16x8 Qf[2][2];
  for (int mi = 0; mi < 2; ++mi)
    for (int kk = 0; kk < 2; ++kk)
      Qf[mi][kk] = *(const bf16x8*)(Qg + base +
                                    (size_t)(q0 + w * 32 + mi * 16 + l15) * 64 +
                                    kk * 32 + quad * 8);

  f32x4 Oa[4][2] = {};
  float lrun[2] = {0.f, 0.f};

  const int lrow = l >> 3, lc = l & 7;
  const int csw = ((lc ^ (lrow & 7)) * 8);
  const bf16_t* kg0 = Kg + base + (size_t)(w * 8 + lrow) * 64 + csw;
  const bf16_t* kg1 = kg0 + 32 * 64;
  const bf16_t* vg0 = Vtg + ((size_t)bh * 64 + w * 8 + lrow) * 2048 + csw;
  const bf16_t* vg1 = vg0 + (size_t)32 * 2048;
  const int lofs = w * 512;

  // prologue: stage tile 0 into buf 0
  GLD_TO_LDS(kg0, KVf + lofs);
  GLD_TO_LDS(kg1, KVf + 2048 + lofs);
  GLD_TO_LDS(vg0, KVf + 4096 + lofs);
  GLD_TO_LDS(vg1, KVf + 6144 + lofs);
  kg0 += 4096; kg1 += 4096; vg0 += 64; vg1 += 64;

  for (int it = 0; it < 32; ++it) {
    bf16_t* Ks = KVf + (it & 1) * 8192;
    bf16_t* Vt = Ks + 4096;
    if (it < 31) {
      // prefetch tile it+1 into the other buffer; keep 4 loads in flight
      bf16_t* Kn = KVf + ((it + 1) & 1) * 8192;
      GLD_TO_LDS(kg0, Kn + lofs);
      GLD_TO_LDS(kg1, Kn + 2048 + lofs);
      GLD_TO_LDS(vg0, Kn + 4096 + lofs);
      GLD_TO_LDS(vg1, Kn + 6144 + lofs);
      kg0 += 4096; kg1 += 4096; vg0 += 64; vg1 += 64;
      asm volatile("s_waitcnt vmcnt(4)" ::: "memory");
    } else {
      asm volatile("s_waitcnt vmcnt(0)" ::: "memory");
    }
    __builtin_amdgcn_s_barrier();
    asm volatile("" ::: "memory");

    f32x4 S[4][2] = {};
    for (int kk = 0; kk < 2; ++kk) {
      bf16x8 af[4];
      for (int nr = 0; nr < 4; ++nr) {
        const int row = nr * 16 + l15, ch = kk * 4 + quad;
        af[nr] = *(const bf16x8*)&Ks[row * 64 + ((ch ^ (row & 7)) * 8)];
      }
      __builtin_amdgcn_s_setprio(1);
      for (int nr = 0; nr < 4; ++nr)
        for (int mi = 0; mi < 2; ++mi)
          S[nr][mi] = MFMA16(af[nr], Qf[mi][kk], S[nr][mi]);
      __builtin_amdgcn_s_setprio(0);
    }

    for (int mi = 0; mi < 2; ++mi) {
      const int prow = mi * 16 + l15;
      float ps = 0.f;
      for (int nr = 0; nr < 4; ++nr) {
        float p[4];
        for (int r = 0; r < 4; ++r) {
          p[r] = exp2f(S[nr][mi][r]);
          ps += p[r];
        }
        const int nbase = nr * 16 + quad * 4;
        const int ch = nbase >> 3, nb7 = nbase & 7;
        bf16x4 pk;
        pk[0] = (bf16_t)p[0]; pk[1] = (bf16_t)p[1];
        pk[2] = (bf16_t)p[2]; pk[3] = (bf16_t)p[3];
        *(bf16x4*)&Pw[prow * 64 + ((ch ^ (prow & 7)) * 8) + nb7] = pk;
      }
      lrun[mi] += ps;
    }
    asm volatile("s_waitcnt lgkmcnt(0)" ::: "memory");

    for (int kk = 0; kk < 2; ++kk) {
      bf16x8 vf[4], pf[2];
      for (int ei = 0; ei < 4; ++ei) {
        const int row = ei * 16 + l15, ch = kk * 4 + quad;
        vf[ei] = *(const bf16x8*)&Vt[row * 64 + ((ch ^ (row & 7)) * 8)];
      }
      for (int mi = 0; mi < 2; ++mi) {
        const int prow = mi * 16 + l15, ch = kk * 4 + quad;
        pf[mi] = *(const bf16x8*)&Pw[prow * 64 + ((ch ^ (prow & 7)) * 8)];
      }
      __builtin_amdgcn_s_setprio(1);
      for (int ei = 0; ei < 4; ++ei)
        for (int mi = 0; mi < 2; ++mi)
          Oa[ei][mi] = MFMA16(vf[ei], pf[mi], Oa[ei][mi]);
      __builtin_amdgcn_s_setprio(0);
    }
    asm volatile("s_waitcnt lgkmcnt(0)" ::: "memory");
    __builtin_amdgcn_s_barrier();
    asm volatile("" ::: "memory");
  }

  for (int mi = 0; mi < 2; ++mi) {
    lrun[mi] += __shfl_xor(lrun[mi], 16);
    lrun[mi] += __shfl_xor(lrun[mi], 32);
  }

  // epilogue: O^T -> token rows via LDS (128x64), coalesced write
  bf16_t* Os = KVf;
  const float inv0 = 1.f / lrun[0], inv1 = 1.f / lrun[1];
  for (int mi = 0; mi < 2; ++mi) {
    const float inv = mi ? inv1 : inv0;
    const int mrow = w * 32 + mi * 16 + l15;
    for (int ei = 0; ei < 4; ++ei) {
      const int e0 = ei * 16 + quad * 4;
      const int ch = e0 >> 3, e7 = e0 & 7;
      bf16x4 q;
      q[0] = (bf16_t)(Oa[ei][mi][0] * inv);
      q[1] = (bf16_t)(Oa[ei][mi][1] * inv);
      q[2] = (bf16_t)(Oa[ei][mi][2] * inv);
      q[3] = (bf16_t)(Oa[ei][mi][3] * inv);
      *(bf16x4*)&Os[mrow * 64 + ((ch ^ (mrow & 7)) * 8) + e7] = q;
    }
  }
  __syncthreads();
  const int b_ = bh / 12, h_ = bh % 12;
  const int row = tid >> 1;
  for (int c = 0; c < 4; ++c) {
    const int ch = (tid & 1) * 4 + c;
    bf16x8 d = *(const bf16x8*)&Os[row * 64 + ((ch ^ (row & 7)) * 8)];
    *(bf16x8*)(AO + ((size_t)(b_ * 2048 + q0 + row)) * 768 + h_ * 64 + ch * 8) = d;
  }
}

// ---------------------------------------------------------------------------
// Fused FFN middle: per block (64 tokens, dff group g of 768):
//   loop 24 chunks of 32 dff: Ht = V1c(A) x mid(B) -> +b1, gelu -> LDS ->
//   acc[tok][256] += H x U2c.  acc stays in registers; write bf16 slice.
// Double-buffered V1/U2 staging with counted vmcnt + raw barriers.
// ---------------------------------------------------------------------------
__global__ __launch_bounds__(256, 2) void ffn_k(const bf16_t* __restrict__ mid,
                                                const bf16_t* __restrict__ V1S,
                                                const bf16_t* __restrict__ U2S,
                                                const bf16_t* __restrict__ b1c,
                                                bf16_t* __restrict__ T2s) {
  __shared__ __attribute__((aligned(16))) bf16_t V1l[2][32 * 256];
  __shared__ __attribute__((aligned(16))) bf16_t U2l[2][256 * 32];
  __shared__ __attribute__((aligned(16))) bf16_t Hl[4][16 * 32];
  __shared__ __attribute__((aligned(16))) bf16_t Bl[768];
  const int tid = threadIdx.x, w = tid >> 6, l = tid & 63;
  const int quad = l >> 4, l15 = l & 15;
  const int m0 = blockIdx.x * 64;
  const int g = blockIdx.y;

  if (tid < 96)
    *(bf16x8*)&Bl[tid * 8] = *(const bf16x8*)(b1c + g * 768 + tid * 8);

  bf16x8 mf[8];
  for (int kk = 0; kk < 8; ++kk)
    mf[kk] = *(const bf16x8*)(mid + (size_t)(m0 + w * 16 + l15) * 256 +
                              kk * 32 + quad * 8);

  f32x4 acc[16] = {};

  const bf16_t* vs = V1S + (size_t)g * 24 * 8192 + w * 512 + l * 8;
  const bf16_t* us = U2S + (size_t)g * 24 * 8192 + w * 512 + l * 8;
  const int lofs = w * 512;

  // prologue: stage chunk 0 into buf 0
  for (int i = 0; i < 4; ++i) {
    GLD_TO_LDS(vs + i * 2048, V1l[0] + lofs + i * 2048);
    GLD_TO_LDS(us + i * 2048, U2l[0] + lofs + i * 2048);
  }
  vs += 8192; us += 8192;

  for (int c = 0; c < 24; ++c) {
    const int cb = c & 1;
    if (c < 23) {
      // prefetch chunk c+1 into the other buffer; keep 8 loads in flight
      for (int i = 0; i < 4; ++i) {
        GLD_TO_LDS(vs + i * 2048, V1l[cb ^ 1] + lofs + i * 2048);
        GLD_TO_LDS(us + i * 2048, U2l[cb ^ 1] + lofs + i * 2048);
      }
      vs += 8192; us += 8192;
      asm volatile("s_waitcnt vmcnt(8)" ::: "memory");
    } else {
      asm volatile("s_waitcnt vmcnt(0)" ::: "memory");
    }
    __builtin_amdgcn_s_barrier();
    asm volatile("" ::: "memory");

    // GEMM1: Ht[d][tok]
    f32x4 S[2] = {};
    for (int kk = 0; kk < 8; ++kk) {
      const int ck = kk * 4 + quad;
      bf16x8 a0 = *(const bf16x8*)&V1l[cb][l15 * 256 + ((ck ^ (l15 & 7)) * 8)];
      bf16x8 a1 =
          *(const bf16x8*)&V1l[cb][(16 + l15) * 256 + ((ck ^ (l15 & 7)) * 8)];
      __builtin_amdgcn_s_setprio(1);
      S[0] = MFMA16(a0, mf[kk], S[0]);
      S[1] = MFMA16(a1, mf[kk], S[1]);
      __builtin_amdgcn_s_setprio(0);
    }
    // bias + gelu, pack into Hl[tok][dff]
    for (int mt = 0; mt < 2; ++mt) {
      bf16x4 bb = *(const bf16x4*)&Bl[c * 32 + mt * 16 + quad * 4];
      bf16x4 hv;
      for (int r = 0; r < 4; ++r) {
        const float v = S[mt][r] + (float)bb[r];
        const float z2 = 2.302589f * (v + 0.044715f * v * v * v);
        hv[r] = (bf16_t)(v / (1.f + exp2f(-z2)));
      }
      const int hch = mt * 2 + (quad >> 1);
      *(bf16x4*)&Hl[w][l15 * 32 + ((hch ^ (l15 & 3)) * 8) + (quad & 1) * 4] = hv;
    }
    asm volatile("s_waitcnt lgkmcnt(0)" ::: "memory");

    // GEMM2: acc[tok][n] += H x U2c
    bf16x8 pa = *(const bf16x8*)&Hl[w][l15 * 32 + ((quad ^ (l15 & 3)) * 8)];
    __builtin_amdgcn_s_setprio(1);
    for (int ni = 0; ni < 16; ++ni) {
      const int n = ni * 16 + l15;
      bf16x8 bfr = *(const bf16x8*)&U2l[cb][n * 32 + ((quad ^ (n & 3)) * 8)];
      acc[ni] = MFMA16(pa, bfr, acc[ni]);
    }
    __builtin_amdgcn_s_setprio(0);
    asm volatile("s_waitcnt lgkmcnt(0)" ::: "memory");
    __builtin_amdgcn_s_barrier();
    asm volatile("" ::: "memory");
  }

  bf16_t* outp = T2s + ((size_t)g * 8192 + m0 + w * 16 + quad * 4) * 256;
  for (int ni = 0; ni < 16; ++ni)
    for (int r = 0; r < 4; ++r)
      outp[(size_t)r * 256 + ni * 16 + l15] = (bf16_t)acc[ni][r];
}

// sum 4 bf16 slices -> bf16
__global__ __launch_bounds__(256) void sum4_k(const bf16_t* __restrict__ T2s,
                                              bf16_t* __restrict__ out) {
  const size_t i = ((size_t)blockIdx.x * 256 + threadIdx.x) * 4;
  f32x4 s = {};
  for (int g = 0; g < 4; ++g) {
    bf16x4 v = *(const bf16x4*)(T2s + (size_t)g * 2097152 + i);
    for (int r = 0; r < 4; ++r) s[r] += (float)v[r];
  }
  bf16x4 o;
  for (int r = 0; r < 4; ++r) o[r] = (bf16_t)s[r];
  *(bf16x4*)(out + i) = o;
}

// ---------------------------------------------------------------------------
// Fused residual + bias + LayerNorm.
// ---------------------------------------------------------------------------
__global__ __launch_bounds__(256) void lnf_k(
    const float* __restrict__ Acc, const void* __restrict__ resid,
    const int* __restrict__ rflag, const bf16_t* __restrict__ bias,
    const bf16_t* __restrict__ g, const bf16_t* __restrict__ b, void* out,
    const int* __restrict__ oflag) {
  const int wv = threadIdx.x >> 6, l = threadIdx.x & 63;
  const int row = blockIdx.x * 4 + wv;
  const int risf = rflag ? *rflag : 0;
  const int f32out = oflag ? *oflag : 0;
  float v[12], s = 0.f, s2 = 0.f;
  for (int j = 0; j < 3; ++j) {
    const int c0 = j * 256 + l * 4;
    const f32x4 a = *(const f32x4*)(Acc + (size_t)row * 768 + c0);
    for (int r = 0; r < 4; ++r) {
      const float f = a[r] + (float)bias[c0 + r] +
                      loadf(resid, (size_t)row * 768 + c0 + r, risf);
      v[j * 4 + r] = f;
      s += f;
      s2 += f * f;
    }
  }
  for (int m = 32; m; m >>= 1) {
    s += __shfl_xor(s, m);
    s2 += __shfl_xor(s2, m);
  }
  const float mu = s * (1.f / 768.f);
  const float var = s2 * (1.f / 768.f) - mu * mu;
  const float rs = rsqrtf(var + 1e-5f);
  for (int j = 0; j < 3; ++j) {
    const int c0 = j * 256 + l * 4;
    if (f32out) {
      f32x4 o;
      for (int r = 0; r < 4; ++r)
        o[r] = (v[j * 4 + r] - mu) * rs * (float)g[c0 + r] + (float)b[c0 + r];
      *(f32x4*)((float*)out + (size_t)row * 768 + c0) = o;
    } else {
      bf16x4 o;
      for (int r = 0; r < 4; ++r)
        o[r] = (bf16_t)((v[j * 4 + r] - mu) * rs * (float)g[c0 + r] +
                        (float)b[c0 + r]);
      *(bf16x4*)((bf16_t*)out + (size_t)row * 768 + c0) = o;
    }
  }
}

// ---------------------------------------------------------------------------
extern "C" void kernel_launch(void* const* d_in, const int* in_sizes, int n_in,
                              void* d_out, int out_size, void* d_ws,
                              size_t ws_size, hipStream_t stream) {
  const void* x   = d_in[0];
  const void* Pq  = d_in[2];
  const void* Vq  = d_in[3];
  const void* bq  = d_in[4];
  const void* Pk  = d_in[5];
  const void* Vk  = d_in[6];
  const void* bk  = d_in[7];
  const void* Pv  = d_in[8];
  const void* Vv  = d_in[9];
  const void* bv  = d_in[10];
  const void* Uo  = d_in[11];
  const void* Vo  = d_in[12];
  const void* bo  = d_in[13];
  const void* U1  = d_in[14];
  const void* V1  = d_in[15];
  const void* b1  = d_in[16];
  const void* U2  = d_in[17];
  const void* V2  = d_in[18];
  const void* b2  = d_in[19];
  const void* g1  = d_in[20];
  const void* be1 = d_in[21];
  const void* g2  = d_in[22];
  const void* be2 = d_in[23];

  // ---- workspace layout, peak 60,182,528 B ----
  char* ws = (char*)d_ws;
  bf16_t* WtQKV = (bf16_t*)(ws + 0);
  bf16_t* UoT   = (bf16_t*)(ws + 3538944);
  bf16_t* VoT   = (bf16_t*)(ws + 3932160);
  bf16_t* U1T   = (bf16_t*)(ws + 4325376);
  bf16_t* V1T   = (bf16_t*)(ws + 4718592);
  bf16_t* U2T   = (bf16_t*)(ws + 6291456);
  bf16_t* V2T   = (bf16_t*)(ws + 7864320);
  bf16_t* Bc    = (bf16_t*)(ws + 8257536);
  int*    flag  = (int*)(ws + 8277504);
  bf16_t* xc    = (bf16_t*)(ws + 8278016);    // 12.58 MB
  bf16_t* Qb    = (bf16_t*)(ws + 20860928);   // 12.58 MB
  bf16_t* Kb    = (bf16_t*)(ws + 33443840);   // 12.58 MB
  bf16_t* Vb    = (bf16_t*)(ws + 46026752);   // -> 58,609,664
  bf16_t* WoT   = (bf16_t*)(ws + 58609664);   // -> 59,789,312
  bf16_t* Uo_c  = (bf16_t*)(ws + 59789312);   // -> 60,182,528
  // aliases (after attention, Qb/Kb/Vb dead):
  bf16_t* AO   = xc;                           // attn out over dead xc
  bf16_t* X1   = AO;                           // LN1 out in place
  bf16_t* T    = Qb;                           // mid / t2 bf16 4.2 MB
  bf16_t* T2s  = (bf16_t*)(ws + 25055232);    // 4 x 4.19 MB -> 41,832,448
  bf16_t* V1S  = (bf16_t*)(ws + 41832448);    // 1.5 MB
  bf16_t* U2S  = (bf16_t*)(ws + 43405312);    // 1.5 MB -> 44,978,176
  float*  Rf   = (float*)(ws + 33443840);     // fp32 25.2 MB (Kb+Vb slots)

  bf16_t* bqkvc = Bc + 0;
  bf16_t* boc   = Bc + 2304;
  bf16_t* b1c   = Bc + 3072;
  bf16_t* b2c   = Bc + 6144;
  bf16_t* g1c   = Bc + 6912;
  bf16_t* be1c  = Bc + 7680;
  bf16_t* g2c   = Bc + 8448;
  bf16_t* be2c  = Bc + 9216;

  // ---- dtype detection + canonicalization + weight prep ----
  detect_k<<<1, 256, 0, stream>>>((const unsigned short*)x, flag);
  cvtin_k<<<4096, 256, 0, stream>>>(x, xc, 8192 * 768, flag);
  cvtin_k<<<768, 256, 0, stream>>>(Uo, Uo_c, 768 * 256, flag);
  bcat_k<<<39, 256, 0, stream>>>(bq, bk, bv, bo, b1, b2, g1, be1, g2, be2, Bc,
                                 flag);
  wqkv_k<<<36, 256, 0, stream>>>(Pq, Vq, Pk, Vk, Pv, Vv, WtQKV, flag);
  transpose_all_k<<<2304, 256, 0, stream>>>(Uo, Vo, U1, V1, U2, V2, UoT, VoT,
                                            U1T, V1T, U2T, V2T, flag);
  gemm64<0><<<dim3(12, 12), 256, 0, stream>>>(VoT, Uo_c, 768, 256, 256, 256,
                                              WoT, nullptr);

  // ---- QKV projection (Q pre-scaled) ----
  gemm_bt<3><<<dim3(18, 64), 256, 0, stream>>>(xc, WtQKV, 2304, 768, 768, 768,
                                               Qb, Kb, Vb, bqkvc);

  // ---- flash attention -> AO ----
  attn_k<<<dim3(16, 48), 256, 0, stream>>>(Qb, Kb, Vb, AO);

  // ---- output projection: Rf = AO@WoT; X1 = LN(x + Rf + bo) ----
  gemm128x64<8><<<dim3(12, 64), 256, 0, stream>>>(AO, WoT, 768, 768, 768, 768,
                                                  nullptr, Rf);
  lnf_k<<<2048, 256, 0, stream>>>(Rf, x, flag, boc, g1c, be1c, X1, nullptr);

  // ---- FFN: mid = X1@U1; fused gelu+U2 contraction; t2@V2; LN2 ----
  swz_k<<<768, 256, 0, stream>>>(V1T, U2T, V1S, U2S);
  gemm64<0><<<dim3(4, 128), 256, 0, stream>>>(X1, U1T, 256, 768, 768, 768, T,
                                              nullptr);
  ffn_k<<<dim3(128, 4), 256, 0, stream>>>(T, V1S, U2S, b1c, T2s);
  sum4_k<<<2048, 256, 0, stream>>>(T2s, T);
  gemm128x64<8><<<dim3(12, 64), 256, 0, stream>>>(T, V2T, 768, 256, 256, 256,
                                                  nullptr, Rf);
  lnf_k<<<2048, 256, 0, stream>>>(Rf, X1, nullptr, b2c, g2c, be2c, d_out, flag);
}

// Round 5
// 498.569 us; speedup vs baseline: 1.0437x; 1.0101x over previous
//
#include <hip/hip_runtime.h>
#include <cmath>

typedef __bf16 bf16_t;
typedef bf16_t bf16x8 __attribute__((ext_vector_type(8)));
typedef bf16_t bf16x4 __attribute__((ext_vector_type(4)));
typedef float f32x4 __attribute__((ext_vector_type(4)));

#define MFMA16(a, b, c) __builtin_amdgcn_mfma_f32_16x16x32_bf16(a, b, c, 0, 0, 0)
#define GLD_TO_LDS(gp, lp)                                                        \
  __builtin_amdgcn_global_load_lds(                                               \
      (const __attribute__((address_space(1))) void*)(gp),                        \
      (__attribute__((address_space(3))) void*)(lp), 16, 0, 0)

__device__ __forceinline__ float loadf(const void* p, size_t i, int isf) {
  return isf ? ((const float*)p)[i] : (float)((const bf16_t*)p)[i];
}

// softmax scale folded into Q: 1/sqrt(64) * log2(e)
#define QSCALE 0.18033688f

// ---------------------------------------------------------------------------
__global__ __launch_bounds__(256) void detect_k(
    const unsigned short* __restrict__ xr, int* __restrict__ flag) {
  __shared__ int s;
  if (threadIdx.x == 0) s = 0;
  __syncthreads();
  int bad = 0;
  for (int i = 0; i < 32; ++i) {
    const unsigned short u = xr[threadIdx.x * 32 + i];
    const int e = (u >> 7) & 0xFF;
    if (e >= 0xC8) bad = 1;
  }
  if (bad) atomicOr(&s, 1);
  __syncthreads();
  if (threadIdx.x == 0) *flag = s;
}

__global__ __launch_bounds__(256) void cvtin_k(const void* __restrict__ src,
                                               bf16_t* __restrict__ dst, int n,
                                               const int* __restrict__ flagp) {
  const int isf = *flagp;
  for (int i = blockIdx.x * 256 + threadIdx.x; i < n; i += gridDim.x * 256)
    dst[i] = (bf16_t)loadf(src, i, isf);
}

__global__ __launch_bounds__(256) void bcat_k(
    const void* bq, const void* bk, const void* bv, const void* bo,
    const void* b1, const void* b2, const void* g1, const void* be1,
    const void* g2, const void* be2, bf16_t* __restrict__ dst,
    const int* __restrict__ flagp) {
  const int isf = *flagp;
  const int i = blockIdx.x * 256 + threadIdx.x;
  if (i >= 9984) return;
  const void* src;
  int off;
  if (i < 768)       { src = bq;  off = i; }
  else if (i < 1536) { src = bk;  off = i - 768; }
  else if (i < 2304) { src = bv;  off = i - 1536; }
  else if (i < 3072) { src = bo;  off = i - 2304; }
  else if (i < 6144) { src = b1;  off = i - 3072; }
  else if (i < 6912) { src = b2;  off = i - 6144; }
  else if (i < 7680) { src = g1;  off = i - 6912; }
  else if (i < 8448) { src = be1; off = i - 7680; }
  else if (i < 9216) { src = g2;  off = i - 8448; }
  else               { src = be2; off = i - 9216; }
  dst[i] = (bf16_t)loadf(src, off, isf);
}

// ---------------------------------------------------------------------------
__global__ __launch_bounds__(256) void wqkv_k(
    const void* __restrict__ Pq, const void* __restrict__ Vq,
    const void* __restrict__ Pk, const void* __restrict__ Vk,
    const void* __restrict__ Pv, const void* __restrict__ Vv,
    bf16_t* __restrict__ Wt, const int* __restrict__ flagp) {
  const int isf = *flagp;
  const int sh = blockIdx.x, s = sh / 12, h = sh % 12;
  const void* P = (s == 0) ? Pq : (s == 1) ? Pk : Pv;
  const void* Vm = (s == 0) ? Vq : (s == 1) ? Vk : Vv;
  __shared__ float Vl[32 * 64];
  const int tid = threadIdx.x;
  for (int i = tid; i < 2048; i += 256)
    Vl[i] = loadf(Vm, (size_t)h * 2048 + i, isf);
  __syncthreads();
  for (int kb = 0; kb < 3; ++kb) {
    const int k = kb * 256 + tid;
    float pr[32];
    const size_t prow = ((size_t)h * 768 + k) * 32;
    for (int r = 0; r < 32; ++r) pr[r] = loadf(P, prow + r, isf);
    for (int e = 0; e < 64; ++e) {
      float a = 0.f;
      for (int r = 0; r < 32; ++r) a += pr[r] * Vl[r * 64 + e];
      Wt[((size_t)sh * 64 + e) * 768 + k] = (bf16_t)a;
    }
  }
}

// ---------------------------------------------------------------------------
__global__ __launch_bounds__(256) void transpose_all_k(
    const void* Uo, const void* Vo, const void* U1, const void* V1,
    const void* U2, const void* V2, bf16_t* UoT, bf16_t* VoT, bf16_t* U1T,
    bf16_t* V1T, bf16_t* U2T, bf16_t* V2T, const int* __restrict__ flagp) {
  const int isf = *flagp;
  int t = blockIdx.x;
  const void* in;
  bf16_t* out;
  int Kd, Nd, bx, by;
  if (t < 192)       { in = Uo; out = UoT; Kd = 768;  Nd = 256;  bx = t & 7;  by = t >> 3; }
  else if (t < 384)  { t -= 192;  in = Vo; out = VoT; Kd = 256;  Nd = 768;  bx = t % 24; by = t / 24; }
  else if (t < 576)  { t -= 384;  in = U1; out = U1T; Kd = 768;  Nd = 256;  bx = t & 7;  by = t >> 3; }
  else if (t < 1344) { t -= 576;  in = V1; out = V1T; Kd = 256;  Nd = 3072; bx = t % 96; by = t / 96; }
  else if (t < 2112) { t -= 1344; in = U2; out = U2T; Kd = 3072; Nd = 256;  bx = t & 7;  by = t >> 3; }
  else               { t -= 2112; in = V2; out = V2T; Kd = 256;  Nd = 768;  bx = t % 24; by = t / 24; }
  __shared__ bf16_t tl[32][33];
  const int X = bx * 32, Y = by * 32;
  const int x = threadIdx.x & 31, y = threadIdx.x >> 5;
  for (int i = 0; i < 32; i += 8)
    tl[y + i][x] = (bf16_t)loadf(in, (size_t)(Y + y + i) * Nd + X + x, isf);
  __syncthreads();
  for (int i = 0; i < 32; i += 8)
    out[(size_t)(X + y + i) * Kd + Y + x] = tl[x][y + i];
}

// ---------------------------------------------------------------------------
// repack V1T/U2T into swizzled, linearly-stageable chunk layouts for ffn_k.
// V1S[ch][dl][c*8+j] = V1T[ch*32+dl][(c^(dl&7))*8 + j]   (ch 0..95, c 0..31)
// U2S[ch][n][c*8+j]  = U2T[n][ch*32 + (c^(n&3))*8 + j]   (c 0..3)
// ---------------------------------------------------------------------------
__global__ __launch_bounds__(256) void swz_k(const bf16_t* __restrict__ V1T,
                                             const bf16_t* __restrict__ U2T,
                                             bf16_t* __restrict__ V1S,
                                             bf16_t* __restrict__ U2S) {
  const int u = blockIdx.x * 256 + threadIdx.x;
  if (u < 98304) {
    const int ch = u >> 10, dl = (u >> 5) & 31, c = u & 31;
    *(bf16x8*)(V1S + (size_t)u * 8) =
        *(const bf16x8*)(V1T + (size_t)(ch * 32 + dl) * 256 +
                         ((c ^ (dl & 7)) * 8));
  } else {
    const int u2 = u - 98304;
    const int ch = u2 >> 10, n = (u2 >> 2) & 255, c = u2 & 3;
    *(bf16x8*)(U2S + (size_t)u2 * 8) =
        *(const bf16x8*)(U2T + (size_t)n * 3072 + ch * 32 +
                         ((c ^ (n & 3)) * 8));
  }
}

// ---------------------------------------------------------------------------
// 128x128-tile GEMM. EPI 3: QKV scatter (+biases), Q pre-scaled, V transposed
// ---------------------------------------------------------------------------
template <int EPI>
__global__ __launch_bounds__(256, 3) void gemm_bt(
    const bf16_t* __restrict__ A, const bf16_t* __restrict__ Bt, int N, int K,
    int lda, int ldb, bf16_t* __restrict__ Qb, bf16_t* __restrict__ Kb,
    bf16_t* __restrict__ Vb, const bf16_t* __restrict__ bqkv) {
  __shared__ __attribute__((aligned(16))) bf16_t As[128 * 64];
  __shared__ __attribute__((aligned(16))) bf16_t Bs[128 * 64];
  const int tid = threadIdx.x;
  const int w = tid >> 6, l = tid & 63;
  const int quad = l >> 4, l15 = l & 15;
  const int m0 = blockIdx.y * 128, n0 = blockIdx.x * 128;

  const bf16_t* gA = A + (size_t)(m0 + w * 32 + (l >> 3)) * lda + (l & 7) * 8;
  const bf16_t* gB = Bt + (size_t)(n0 + w * 32 + (l >> 3)) * ldb + (l & 7) * 8;
  bf16_t* lA = &As[(w * 32) * 64];
  bf16_t* lB = &Bs[(w * 32) * 64];

  f32x4 acc[4][4] = {};
  const int wm = (w >> 1) * 64, wn = (w & 1) * 64;

  for (int k0 = 0; k0 < K; k0 += 64) {
    for (int c = 0; c < 4; ++c) {
      GLD_TO_LDS(gA + (size_t)(c * 8) * lda + k0, lA + (c * 8) * 64);
      GLD_TO_LDS(gB + (size_t)(c * 8) * ldb + k0, lB + (c * 8) * 64);
    }
    __syncthreads();
    for (int kk = 0; kk < 2; ++kk) {
      bf16x8 af[4], bfr[4];
      for (int i = 0; i < 4; ++i)
        af[i] = *(const bf16x8*)&As[(wm + i * 16 + l15) * 64 + kk * 32 + quad * 8];
      for (int i = 0; i < 4; ++i)
        bfr[i] = *(const bf16x8*)&Bs[(wn + i * 16 + l15) * 64 + kk * 32 + quad * 8];
      for (int mi = 0; mi < 4; ++mi)
        for (int ni = 0; ni < 4; ++ni)
          acc[mi][ni] = MFMA16(af[mi], bfr[ni], acc[mi][ni]);
    }
    __syncthreads();
  }

  for (int mi = 0; mi < 4; ++mi) {
    for (int ni = 0; ni < 4; ++ni) {
      const int gn = n0 + wn + ni * 16 + l15;
      const int s = gn / 768, rem = gn - s * 768;
      const int h = rem >> 6, e = rem & 63;
      const float bvv = (float)bqkv[gn];
      for (int r = 0; r < 4; ++r) {
        const int gm = m0 + wm + mi * 16 + quad * 4 + r;
        const int b_ = gm >> 11, mloc = gm & 2047;
        const int bh = b_ * 12 + h;
        float v = acc[mi][ni][r] + bvv;
        if (s == 0) {
          Qb[((size_t)bh * 2048 + mloc) * 64 + e] = (bf16_t)(v * QSCALE);
        } else if (s == 1) {
          Kb[((size_t)bh * 2048 + mloc) * 64 + e] = (bf16_t)v;
        } else {
          Vb[((size_t)bh * 64 + e) * 2048 + mloc] = (bf16_t)v;  // transposed
        }
      }
    }
  }
}

// ---------------------------------------------------------------------------
// 64x64-tile GEMM (skinny). EPI 0: bf16 store | 8: Cf = acc (fp32)
// ---------------------------------------------------------------------------
template <int EPI>
__global__ __launch_bounds__(256, 4) void gemm64(
    const bf16_t* __restrict__ A, const bf16_t* __restrict__ Bt, int N, int K,
    int lda, int ldb, bf16_t* __restrict__ Cb, float* __restrict__ Cf) {
  __shared__ __attribute__((aligned(16))) bf16_t As[64 * 64];
  __shared__ __attribute__((aligned(16))) bf16_t Bs[64 * 64];
  const int tid = threadIdx.x;
  const int w = tid >> 6, l = tid & 63;
  const int quad = l >> 4, l15 = l & 15;
  const int m0 = blockIdx.y * 64, n0 = blockIdx.x * 64;

  const bf16_t* gA = A + (size_t)(m0 + w * 16 + (l >> 3)) * lda + (l & 7) * 8;
  const bf16_t* gB = Bt + (size_t)(n0 + w * 16 + (l >> 3)) * ldb + (l & 7) * 8;
  bf16_t* lA = &As[(w * 16) * 64];
  bf16_t* lB = &Bs[(w * 16) * 64];

  f32x4 acc[4] = {};

  for (int k0 = 0; k0 < K; k0 += 64) {
    for (int c = 0; c < 2; ++c) {
      GLD_TO_LDS(gA + (size_t)(c * 8) * lda + k0, lA + (c * 8) * 64);
      GLD_TO_LDS(gB + (size_t)(c * 8) * ldb + k0, lB + (c * 8) * 64);
    }
    __syncthreads();
    for (int kk = 0; kk < 2; ++kk) {
      bf16x8 af = *(const bf16x8*)&As[(w * 16 + l15) * 64 + kk * 32 + quad * 8];
      bf16x8 bfr[4];
      for (int i = 0; i < 4; ++i)
        bfr[i] = *(const bf16x8*)&Bs[(i * 16 + l15) * 64 + kk * 32 + quad * 8];
      for (int ni = 0; ni < 4; ++ni) acc[ni] = MFMA16(af, bfr[ni], acc[ni]);
    }
    __syncthreads();
  }

  for (int ni = 0; ni < 4; ++ni) {
    const int gn = n0 + ni * 16 + l15;
    for (int r = 0; r < 4; ++r) {
      const int gm = m0 + w * 16 + quad * 4 + r;
      if (EPI == 0)
        Cb[(size_t)gm * N + gn] = (bf16_t)acc[ni][r];
      else
        Cf[(size_t)gm * N + gn] = acc[ni][r];
    }
  }
}

// ---------------------------------------------------------------------------
// 128x64-tile GEMM for tall-skinny shapes (M large). 4 waves = 2M x 2N of
// 64x32 each; 16 MFMA/wave/K-step (2x gemm64 density). EPI 0/8 as gemm64.
// ---------------------------------------------------------------------------
template <int EPI>
__global__ __launch_bounds__(256, 3) void gemm128x64(
    const bf16_t* __restrict__ A, const bf16_t* __restrict__ Bt, int N, int K,
    int lda, int ldb, bf16_t* __restrict__ Cb, float* __restrict__ Cf) {
  __shared__ __attribute__((aligned(16))) bf16_t As[128 * 64];
  __shared__ __attribute__((aligned(16))) bf16_t Bs[64 * 64];
  const int tid = threadIdx.x;
  const int w = tid >> 6, l = tid & 63;
  const int quad = l >> 4, l15 = l & 15;
  const int m0 = blockIdx.y * 128, n0 = blockIdx.x * 64;

  const bf16_t* gA = A + (size_t)(m0 + w * 32 + (l >> 3)) * lda + (l & 7) * 8;
  const bf16_t* gB = Bt + (size_t)(n0 + w * 16 + (l >> 3)) * ldb + (l & 7) * 8;
  bf16_t* lA = &As[(w * 32) * 64];
  bf16_t* lB = &Bs[(w * 16) * 64];

  f32x4 acc[4][2] = {};
  const int wm = (w >> 1) * 64, wn = (w & 1) * 32;

  for (int k0 = 0; k0 < K; k0 += 64) {
    for (int c = 0; c < 4; ++c)
      GLD_TO_LDS(gA + (size_t)(c * 8) * lda + k0, lA + (c * 8) * 64);
    for (int c = 0; c < 2; ++c)
      GLD_TO_LDS(gB + (size_t)(c * 8) * ldb + k0, lB + (c * 8) * 64);
    __syncthreads();
    for (int kk = 0; kk < 2; ++kk) {
      bf16x8 af[4], bfr[2];
      for (int i = 0; i < 4; ++i)
        af[i] = *(const bf16x8*)&As[(wm + i * 16 + l15) * 64 + kk * 32 + quad * 8];
      for (int i = 0; i < 2; ++i)
        bfr[i] = *(const bf16x8*)&Bs[(wn + i * 16 + l15) * 64 + kk * 32 + quad * 8];
      for (int mi = 0; mi < 4; ++mi)
        for (int ni = 0; ni < 2; ++ni)
          acc[mi][ni] = MFMA16(af[mi], bfr[ni], acc[mi][ni]);
    }
    __syncthreads();
  }

  for (int mi = 0; mi < 4; ++mi) {
    for (int ni = 0; ni < 2; ++ni) {
      const int gn = n0 + wn + ni * 16 + l15;
      for (int r = 0; r < 4; ++r) {
        const int gm = m0 + wm + mi * 16 + quad * 4 + r;
        if (EPI == 0)
          Cb[(size_t)gm * N + gn] = (bf16_t)acc[mi][ni][r];
        else
          Cf[(size_t)gm * N + gn] = acc[mi][ni][r];
      }
    }
  }
}

// ---------------------------------------------------------------------------
// Flash attention, 128-row Q tiles (32 q-rows/wave), 1-D grid of 768.
// XCD-grouped block mapping: all 16 q-tiles of a head land on one XCD
// (bijective: xcd = d&7, bh = xcd*6 + (d>>3)/16, qt = (d>>3)%16).
// SINGLE barrier per KV-iteration: prefetch is issued after the barrier into
// the other buffer; barrier semantics guarantee all waves consumed the
// previous tile's LDS reads (MFMA use forces lgkm wait) before overwrite.
// ---------------------------------------------------------------------------
__global__ __launch_bounds__(256, 3) void attn_k(const bf16_t* __restrict__ Qg,
                                                 const bf16_t* __restrict__ Kg,
                                                 const bf16_t* __restrict__ Vtg,
                                                 bf16_t* __restrict__ AO) {
  // [buf 0|1][ K(64x64) | V(64x64) ]  = 32 KB
  __shared__ __attribute__((aligned(16))) bf16_t KVf[2 * 2 * 64 * 64];
  __shared__ __attribute__((aligned(16))) bf16_t Pwf[4 * 32 * 64];
  const int tid = threadIdx.x, w = tid >> 6, l = tid & 63;
  const int quad = l >> 4, l15 = l & 15;
  bf16_t* Pw = Pwf + w * 32 * 64;
  const int d = blockIdx.x;
  const int xcd = d & 7, slot = d >> 3;
  const int bh = xcd * 6 + (slot >> 4);
  const int q0 = (slot & 15) * 128;
  const size_t base = (size_t)bh * 2048 * 64;

  bf16x8 Qf[2][2];
  for (int mi = 0; mi < 2; ++mi)
    for (int kk = 0; kk < 2; ++kk)
      Qf[mi][kk] = *(const bf16x8*)(Qg + base +
                                    (size_t)(q0 + w * 32 + mi * 16 + l15) * 64 +
                                    kk * 32 + quad * 8);

  f32x4 Oa[4][2] = {};
  float lrun[2] = {0.f, 0.f};

  const int lrow = l >> 3, lc = l & 7;
  const int csw = ((lc ^ (lrow & 7)) * 8);
  const bf16_t* kg0 = Kg + base + (size_t)(w * 8 + lrow) * 64 + csw;
  const bf16_t* kg1 = kg0 + 32 * 64;
  const bf16_t* vg0 = Vtg + ((size_t)bh * 64 + w * 8 + lrow) * 2048 + csw;
  const bf16_t* vg1 = vg0 + (size_t)32 * 2048;
  const int lofs = w * 512;

  // prologue: stage tile 0 into buf 0
  GLD_TO_LDS(kg0, KVf + lofs);
  GLD_TO_LDS(kg1, KVf + 2048 + lofs);
  GLD_TO_LDS(vg0, KVf + 4096 + lofs);
  GLD_TO_LDS(vg1, KVf + 6144 + lofs);
  kg0 += 4096; kg1 += 4096; vg0 += 64; vg1 += 64;

  for (int it = 0; it < 32; ++it) {
    bf16_t* Ks = KVf + (it & 1) * 8192;
    bf16_t* Vt = Ks + 4096;
    // current tile's 4 loads are the only outstanding VMEM ops (issued one
    // full iteration ago) — drain them, then sync.
    asm volatile("s_waitcnt vmcnt(0)" ::: "memory");
    __builtin_amdgcn_s_barrier();
    asm volatile("" ::: "memory");
    if (it < 31) {
      // prefetch tile it+1 into the other buffer (safe: all waves are now in
      // iter `it`, which only reads buf[it&1]).
      bf16_t* Kn = KVf + ((it + 1) & 1) * 8192;
      GLD_TO_LDS(kg0, Kn + lofs);
      GLD_TO_LDS(kg1, Kn + 2048 + lofs);
      GLD_TO_LDS(vg0, Kn + 4096 + lofs);
      GLD_TO_LDS(vg1, Kn + 6144 + lofs);
      kg0 += 4096; kg1 += 4096; vg0 += 64; vg1 += 64;
    }

    f32x4 S[4][2] = {};
    for (int kk = 0; kk < 2; ++kk) {
      bf16x8 af[4];
      for (int nr = 0; nr < 4; ++nr) {
        const int row = nr * 16 + l15, ch = kk * 4 + quad;
        af[nr] = *(const bf16x8*)&Ks[row * 64 + ((ch ^ (row & 7)) * 8)];
      }
      __builtin_amdgcn_s_setprio(1);
      for (int nr = 0; nr < 4; ++nr)
        for (int mi = 0; mi < 2; ++mi)
          S[nr][mi] = MFMA16(af[nr], Qf[mi][kk], S[nr][mi]);
      __builtin_amdgcn_s_setprio(0);
    }

    for (int mi = 0; mi < 2; ++mi) {
      const int prow = mi * 16 + l15;
      float ps = 0.f;
      for (int nr = 0; nr < 4; ++nr) {
        float p[4];
        for (int r = 0; r < 4; ++r) {
          p[r] = exp2f(S[nr][mi][r]);
          ps += p[r];
        }
        const int nbase = nr * 16 + quad * 4;
        const int ch = nbase >> 3, nb7 = nbase & 7;
        bf16x4 pk;
        pk[0] = (bf16_t)p[0]; pk[1] = (bf16_t)p[1];
        pk[2] = (bf16_t)p[2]; pk[3] = (bf16_t)p[3];
        *(bf16x4*)&Pw[prow * 64 + ((ch ^ (prow & 7)) * 8) + nb7] = pk;
      }
      lrun[mi] += ps;
    }
    asm volatile("s_waitcnt lgkmcnt(0)" ::: "memory");

    for (int kk = 0; kk < 2; ++kk) {
      bf16x8 vf[4], pf[2];
      for (int ei = 0; ei < 4; ++ei) {
        const int row = ei * 16 + l15, ch = kk * 4 + quad;
        vf[ei] = *(const bf16x8*)&Vt[row * 64 + ((ch ^ (row & 7)) * 8)];
      }
      for (int mi = 0; mi < 2; ++mi) {
        const int prow = mi * 16 + l15, ch = kk * 4 + quad;
        pf[mi] = *(const bf16x8*)&Pw[prow * 64 + ((ch ^ (prow & 7)) * 8)];
      }
      __builtin_amdgcn_s_setprio(1);
      for (int ei = 0; ei < 4; ++ei)
        for (int mi = 0; mi < 2; ++mi)
          Oa[ei][mi] = MFMA16(vf[ei], pf[mi], Oa[ei][mi]);
      __builtin_amdgcn_s_setprio(0);
    }
    // no end-of-iteration barrier: next iter's top barrier provides the sync.
  }

  for (int mi = 0; mi < 2; ++mi) {
    lrun[mi] += __shfl_xor(lrun[mi], 16);
    lrun[mi] += __shfl_xor(lrun[mi], 32);
  }

  // epilogue: O^T -> token rows via LDS (128x64), coalesced write.
  // Os = buf0 region; in the final iter (it=31) all waves read only buf1/Pw,
  // so buf0 is free for reuse without an extra barrier before the writes.
  bf16_t* Os = KVf;
  const float inv0 = 1.f / lrun[0], inv1 = 1.f / lrun[1];
  for (int mi = 0; mi < 2; ++mi) {
    const float inv = mi ? inv1 : inv0;
    const int mrow = w * 32 + mi * 16 + l15;
    for (int ei = 0; ei < 4; ++ei) {
      const int e0 = ei * 16 + quad * 4;
      const int ch = e0 >> 3, e7 = e0 & 7;
      bf16x4 q;
      q[0] = (bf16_t)(Oa[ei][mi][0] * inv);
      q[1] = (bf16_t)(Oa[ei][mi][1] * inv);
      q[2] = (bf16_t)(Oa[ei][mi][2] * inv);
      q[3] = (bf16_t)(Oa[ei][mi][3] * inv);
      *(bf16x4*)&Os[mrow * 64 + ((ch ^ (mrow & 7)) * 8) + e7] = q;
    }
  }
  __syncthreads();
  const int b_ = bh / 12, h_ = bh % 12;
  const int row = tid >> 1;
  for (int c = 0; c < 4; ++c) {
    const int ch = (tid & 1) * 4 + c;
    bf16x8 dd = *(const bf16x8*)&Os[row * 64 + ((ch ^ (row & 7)) * 8)];
    *(bf16x8*)(AO + ((size_t)(b_ * 2048 + q0 + row)) * 768 + h_ * 64 + ch * 8) = dd;
  }
}

// ---------------------------------------------------------------------------
// Fused FFN middle: per block (64 tokens, dff group g of 768):
//   loop 24 chunks of 32 dff: Ht = V1c(A) x mid(B) -> +b1, gelu -> LDS ->
//   acc[tok][256] += H x U2c.  acc stays in registers; write bf16 slice.
// Single barrier per chunk (same safety argument as attn_k).
// ---------------------------------------------------------------------------
__global__ __launch_bounds__(256, 2) void ffn_k(const bf16_t* __restrict__ mid,
                                                const bf16_t* __restrict__ V1S,
                                                const bf16_t* __restrict__ U2S,
                                                const bf16_t* __restrict__ b1c,
                                                bf16_t* __restrict__ T2s) {
  __shared__ __attribute__((aligned(16))) bf16_t V1l[2][32 * 256];
  __shared__ __attribute__((aligned(16))) bf16_t U2l[2][256 * 32];
  __shared__ __attribute__((aligned(16))) bf16_t Hl[4][16 * 32];
  __shared__ __attribute__((aligned(16))) bf16_t Bl[768];
  const int tid = threadIdx.x, w = tid >> 6, l = tid & 63;
  const int quad = l >> 4, l15 = l & 15;
  const int m0 = blockIdx.x * 64;
  const int g = blockIdx.y;

  if (tid < 96)
    *(bf16x8*)&Bl[tid * 8] = *(const bf16x8*)(b1c + g * 768 + tid * 8);

  bf16x8 mf[8];
  for (int kk = 0; kk < 8; ++kk)
    mf[kk] = *(const bf16x8*)(mid + (size_t)(m0 + w * 16 + l15) * 256 +
                              kk * 32 + quad * 8);

  f32x4 acc[16] = {};

  const bf16_t* vs = V1S + (size_t)g * 24 * 8192 + w * 512 + l * 8;
  const bf16_t* us = U2S + (size_t)g * 24 * 8192 + w * 512 + l * 8;
  const int lofs = w * 512;

  // prologue: stage chunk 0 into buf 0
  for (int i = 0; i < 4; ++i) {
    GLD_TO_LDS(vs + i * 2048, V1l[0] + lofs + i * 2048);
    GLD_TO_LDS(us + i * 2048, U2l[0] + lofs + i * 2048);
  }
  vs += 8192; us += 8192;

  for (int c = 0; c < 24; ++c) {
    const int cb = c & 1;
    asm volatile("s_waitcnt vmcnt(0)" ::: "memory");
    __builtin_amdgcn_s_barrier();
    asm volatile("" ::: "memory");
    if (c < 23) {
      // prefetch chunk c+1 into the other buffer (all waves now in chunk c)
      for (int i = 0; i < 4; ++i) {
        GLD_TO_LDS(vs + i * 2048, V1l[cb ^ 1] + lofs + i * 2048);
        GLD_TO_LDS(us + i * 2048, U2l[cb ^ 1] + lofs + i * 2048);
      }
      vs += 8192; us += 8192;
    }

    // GEMM1: Ht[d][tok]
    f32x4 S[2] = {};
    for (int kk = 0; kk < 8; ++kk) {
      const int ck = kk * 4 + quad;
      bf16x8 a0 = *(const bf16x8*)&V1l[cb][l15 * 256 + ((ck ^ (l15 & 7)) * 8)];
      bf16x8 a1 =
          *(const bf16x8*)&V1l[cb][(16 + l15) * 256 + ((ck ^ (l15 & 7)) * 8)];
      __builtin_amdgcn_s_setprio(1);
      S[0] = MFMA16(a0, mf[kk], S[0]);
      S[1] = MFMA16(a1, mf[kk], S[1]);
      __builtin_amdgcn_s_setprio(0);
    }
    // bias + gelu, pack into Hl[tok][dff]
    for (int mt = 0; mt < 2; ++mt) {
      bf16x4 bb = *(const bf16x4*)&Bl[c * 32 + mt * 16 + quad * 4];
      bf16x4 hv;
      for (int r = 0; r < 4; ++r) {
        const float v = S[mt][r] + (float)bb[r];
        const float z2 = 2.302589f * (v + 0.044715f * v * v * v);
        hv[r] = (bf16_t)(v / (1.f + exp2f(-z2)));
      }
      const int hch = mt * 2 + (quad >> 1);
      *(bf16x4*)&Hl[w][l15 * 32 + ((hch ^ (l15 & 3)) * 8) + (quad & 1) * 4] = hv;
    }
    asm volatile("s_waitcnt lgkmcnt(0)" ::: "memory");

    // GEMM2: acc[tok][n] += H x U2c
    bf16x8 pa = *(const bf16x8*)&Hl[w][l15 * 32 + ((quad ^ (l15 & 3)) * 8)];
    __builtin_amdgcn_s_setprio(1);
    for (int ni = 0; ni < 16; ++ni) {
      const int n = ni * 16 + l15;
      bf16x8 bfr = *(const bf16x8*)&U2l[cb][n * 32 + ((quad ^ (n & 3)) * 8)];
      acc[ni] = MFMA16(pa, bfr, acc[ni]);
    }
    __builtin_amdgcn_s_setprio(0);
    // no end-of-chunk barrier
  }

  bf16_t* outp = T2s + ((size_t)g * 8192 + m0 + w * 16 + quad * 4) * 256;
  for (int ni = 0; ni < 16; ++ni)
    for (int r = 0; r < 4; ++r)
      outp[(size_t)r * 256 + ni * 16 + l15] = (bf16_t)acc[ni][r];
}

// sum 4 bf16 slices -> bf16
__global__ __launch_bounds__(256) void sum4_k(const bf16_t* __restrict__ T2s,
                                              bf16_t* __restrict__ out) {
  const size_t i = ((size_t)blockIdx.x * 256 + threadIdx.x) * 4;
  f32x4 s = {};
  for (int g = 0; g < 4; ++g) {
    bf16x4 v = *(const bf16x4*)(T2s + (size_t)g * 2097152 + i);
    for (int r = 0; r < 4; ++r) s[r] += (float)v[r];
  }
  bf16x4 o;
  for (int r = 0; r < 4; ++r) o[r] = (bf16_t)s[r];
  *(bf16x4*)(out + i) = o;
}

// ---------------------------------------------------------------------------
// Fused residual + bias + LayerNorm.
// ---------------------------------------------------------------------------
__global__ __launch_bounds__(256) void lnf_k(
    const float* __restrict__ Acc, const void* __restrict__ resid,
    const int* __restrict__ rflag, const bf16_t* __restrict__ bias,
    const bf16_t* __restrict__ g, const bf16_t* __restrict__ b, void* out,
    const int* __restrict__ oflag) {
  const int wv = threadIdx.x >> 6, l = threadIdx.x & 63;
  const int row = blockIdx.x * 4 + wv;
  const int risf = rflag ? *rflag : 0;
  const int f32out = oflag ? *oflag : 0;
  float v[12], s = 0.f, s2 = 0.f;
  for (int j = 0; j < 3; ++j) {
    const int c0 = j * 256 + l * 4;
    const f32x4 a = *(const f32x4*)(Acc + (size_t)row * 768 + c0);
    for (int r = 0; r < 4; ++r) {
      const float f = a[r] + (float)bias[c0 + r] +
                      loadf(resid, (size_t)row * 768 + c0 + r, risf);
      v[j * 4 + r] = f;
      s += f;
      s2 += f * f;
    }
  }
  for (int m = 32; m; m >>= 1) {
    s += __shfl_xor(s, m);
    s2 += __shfl_xor(s2, m);
  }
  const float mu = s * (1.f / 768.f);
  const float var = s2 * (1.f / 768.f) - mu * mu;
  const float rs = rsqrtf(var + 1e-5f);
  for (int j = 0; j < 3; ++j) {
    const int c0 = j * 256 + l * 4;
    if (f32out) {
      f32x4 o;
      for (int r = 0; r < 4; ++r)
        o[r] = (v[j * 4 + r] - mu) * rs * (float)g[c0 + r] + (float)b[c0 + r];
      *(f32x4*)((float*)out + (size_t)row * 768 + c0) = o;
    } else {
      bf16x4 o;
      for (int r = 0; r < 4; ++r)
        o[r] = (bf16_t)((v[j * 4 + r] - mu) * rs * (float)g[c0 + r] +
                        (float)b[c0 + r]);
      *(bf16x4*)((bf16_t*)out + (size_t)row * 768 + c0) = o;
    }
  }
}

// ---------------------------------------------------------------------------
extern "C" void kernel_launch(void* const* d_in, const int* in_sizes, int n_in,
                              void* d_out, int out_size, void* d_ws,
                              size_t ws_size, hipStream_t stream) {
  const void* x   = d_in[0];
  const void* Pq  = d_in[2];
  const void* Vq  = d_in[3];
  const void* bq  = d_in[4];
  const void* Pk  = d_in[5];
  const void* Vk  = d_in[6];
  const void* bk  = d_in[7];
  const void* Pv  = d_in[8];
  const void* Vv  = d_in[9];
  const void* bv  = d_in[10];
  const void* Uo  = d_in[11];
  const void* Vo  = d_in[12];
  const void* bo  = d_in[13];
  const void* U1  = d_in[14];
  const void* V1  = d_in[15];
  const void* b1  = d_in[16];
  const void* U2  = d_in[17];
  const void* V2  = d_in[18];
  const void* b2  = d_in[19];
  const void* g1  = d_in[20];
  const void* be1 = d_in[21];
  const void* g2  = d_in[22];
  const void* be2 = d_in[23];

  // ---- workspace layout, peak 60,182,528 B ----
  char* ws = (char*)d_ws;
  bf16_t* WtQKV = (bf16_t*)(ws + 0);
  bf16_t* UoT   = (bf16_t*)(ws + 3538944);
  bf16_t* VoT   = (bf16_t*)(ws + 3932160);
  bf16_t* U1T   = (bf16_t*)(ws + 4325376);
  bf16_t* V1T   = (bf16_t*)(ws + 4718592);
  bf16_t* U2T   = (bf16_t*)(ws + 6291456);
  bf16_t* V2T   = (bf16_t*)(ws + 7864320);
  bf16_t* Bc    = (bf16_t*)(ws + 8257536);
  int*    flag  = (int*)(ws + 8277504);
  bf16_t* xc    = (bf16_t*)(ws + 8278016);    // 12.58 MB
  bf16_t* Qb    = (bf16_t*)(ws + 20860928);   // 12.58 MB
  bf16_t* Kb    = (bf16_t*)(ws + 33443840);   // 12.58 MB
  bf16_t* Vb    = (bf16_t*)(ws + 46026752);   // -> 58,609,664
  bf16_t* WoT   = (bf16_t*)(ws + 58609664);   // -> 59,789,312
  bf16_t* Uo_c  = (bf16_t*)(ws + 59789312);   // -> 60,182,528
  // aliases (after attention, Qb/Kb/Vb dead):
  bf16_t* AO   = xc;                           // attn out over dead xc
  bf16_t* X1   = AO;                           // LN1 out in place
  bf16_t* T    = Qb;                           // mid / t2 bf16 4.2 MB
  bf16_t* T2s  = (bf16_t*)(ws + 25055232);    // 4 x 4.19 MB -> 41,832,448
  bf16_t* V1S  = (bf16_t*)(ws + 41832448);    // 1.5 MB
  bf16_t* U2S  = (bf16_t*)(ws + 43405312);    // 1.5 MB -> 44,978,176
  float*  Rf   = (float*)(ws + 33443840);     // fp32 25.2 MB (Kb+Vb slots)

  bf16_t* bqkvc = Bc + 0;
  bf16_t* boc   = Bc + 2304;
  bf16_t* b1c   = Bc + 3072;
  bf16_t* b2c   = Bc + 6144;
  bf16_t* g1c   = Bc + 6912;
  bf16_t* be1c  = Bc + 7680;
  bf16_t* g2c   = Bc + 8448;
  bf16_t* be2c  = Bc + 9216;

  // ---- dtype detection + canonicalization + weight prep ----
  detect_k<<<1, 256, 0, stream>>>((const unsigned short*)x, flag);
  cvtin_k<<<4096, 256, 0, stream>>>(x, xc, 8192 * 768, flag);
  cvtin_k<<<768, 256, 0, stream>>>(Uo, Uo_c, 768 * 256, flag);
  bcat_k<<<39, 256, 0, stream>>>(bq, bk, bv, bo, b1, b2, g1, be1, g2, be2, Bc,
                                 flag);
  wqkv_k<<<36, 256, 0, stream>>>(Pq, Vq, Pk, Vk, Pv, Vv, WtQKV, flag);
  transpose_all_k<<<2304, 256, 0, stream>>>(Uo, Vo, U1, V1, U2, V2, UoT, VoT,
                                            U1T, V1T, U2T, V2T, flag);
  gemm64<0><<<dim3(12, 12), 256, 0, stream>>>(VoT, Uo_c, 768, 256, 256, 256,
                                              WoT, nullptr);

  // ---- QKV projection (Q pre-scaled) ----
  gemm_bt<3><<<dim3(18, 64), 256, 0, stream>>>(xc, WtQKV, 2304, 768, 768, 768,
                                               Qb, Kb, Vb, bqkvc);

  // ---- flash attention -> AO ----
  attn_k<<<768, 256, 0, stream>>>(Qb, Kb, Vb, AO);

  // ---- output projection: Rf = AO@WoT; X1 = LN(x + Rf + bo) ----
  gemm128x64<8><<<dim3(12, 64), 256, 0, stream>>>(AO, WoT, 768, 768, 768, 768,
                                                  nullptr, Rf);
  lnf_k<<<2048, 256, 0, stream>>>(Rf, x, flag, boc, g1c, be1c, X1, nullptr);

  // ---- FFN: mid = X1@U1; fused gelu+U2 contraction; t2@V2; LN2 ----
  swz_k<<<768, 256, 0, stream>>>(V1T, U2T, V1S, U2S);
  gemm64<0><<<dim3(4, 128), 256, 0, stream>>>(X1, U1T, 256, 768, 768, 768, T,
                                              nullptr);
  ffn_k<<<dim3(128, 4), 256, 0, stream>>>(T, V1S, U2S, b1c, T2s);
  sum4_k<<<2048, 256, 0, stream>>>(T2s, T);
  gemm128x64<8><<<dim3(12, 64), 256, 0, stream>>>(T, V2T, 768, 256, 256, 256,
                                                  nullptr, Rf);
  lnf_k<<<2048, 256, 0, stream>>>(Rf, X1, nullptr, b2c, g2c, be2c, d_out, flag);
}

// Round 9
// 498.437 us; speedup vs baseline: 1.0440x; 1.0003x over previous
//
#include <hip/hip_runtime.h>
#include <cmath>

typedef __bf16 bf16_t;
typedef bf16_t bf16x8 __attribute__((ext_vector_type(8)));
typedef bf16_t bf16x4 __attribute__((ext_vector_type(4)));
typedef float f32x4 __attribute__((ext_vector_type(4)));

#define MFMA16(a, b, c) __builtin_amdgcn_mfma_f32_16x16x32_bf16(a, b, c, 0, 0, 0)
#define GLD_TO_LDS(gp, lp)                                                        \
  __builtin_amdgcn_global_load_lds(                                               \
      (const __attribute__((address_space(1))) void*)(gp),                        \
      (__attribute__((address_space(3))) void*)(lp), 16, 0, 0)

__device__ __forceinline__ float loadf(const void* p, size_t i, int isf) {
  return isf ? ((const float*)p)[i] : (float)((const bf16_t*)p)[i];
}

// softmax scale folded into Q: 1/sqrt(64) * log2(e)
#define QSCALE 0.18033688f

// ---------------------------------------------------------------------------
__global__ __launch_bounds__(256) void detect_k(
    const unsigned short* __restrict__ xr, int* __restrict__ flag) {
  __shared__ int s;
  if (threadIdx.x == 0) s = 0;
  __syncthreads();
  int bad = 0;
  for (int i = 0; i < 32; ++i) {
    const unsigned short u = xr[threadIdx.x * 32 + i];
    const int e = (u >> 7) & 0xFF;
    if (e >= 0xC8) bad = 1;
  }
  if (bad) atomicOr(&s, 1);
  __syncthreads();
  if (threadIdx.x == 0) *flag = s;
}

__global__ __launch_bounds__(256) void cvtin_k(const void* __restrict__ src,
                                               bf16_t* __restrict__ dst, int n,
                                               const int* __restrict__ flagp) {
  const int isf = *flagp;
  for (int i = blockIdx.x * 256 + threadIdx.x; i < n; i += gridDim.x * 256)
    dst[i] = (bf16_t)loadf(src, i, isf);
}

__global__ __launch_bounds__(256) void bcat_k(
    const void* bq, const void* bk, const void* bv, const void* bo,
    const void* b1, const void* b2, const void* g1, const void* be1,
    const void* g2, const void* be2, bf16_t* __restrict__ dst,
    const int* __restrict__ flagp) {
  const int isf = *flagp;
  const int i = blockIdx.x * 256 + threadIdx.x;
  if (i >= 9984) return;
  const void* src;
  int off;
  if (i < 768)       { src = bq;  off = i; }
  else if (i < 1536) { src = bk;  off = i - 768; }
  else if (i < 2304) { src = bv;  off = i - 1536; }
  else if (i < 3072) { src = bo;  off = i - 2304; }
  else if (i < 6144) { src = b1;  off = i - 3072; }
  else if (i < 6912) { src = b2;  off = i - 6144; }
  else if (i < 7680) { src = g1;  off = i - 6912; }
  else if (i < 8448) { src = be1; off = i - 7680; }
  else if (i < 9216) { src = g2;  off = i - 8448; }
  else               { src = be2; off = i - 9216; }
  dst[i] = (bf16_t)loadf(src, off, isf);
}

// ---------------------------------------------------------------------------
__global__ __launch_bounds__(256) void wqkv_k(
    const void* __restrict__ Pq, const void* __restrict__ Vq,
    const void* __restrict__ Pk, const void* __restrict__ Vk,
    const void* __restrict__ Pv, const void* __restrict__ Vv,
    bf16_t* __restrict__ Wt, const int* __restrict__ flagp) {
  const int isf = *flagp;
  const int sh = blockIdx.x, s = sh / 12, h = sh % 12;
  const void* P = (s == 0) ? Pq : (s == 1) ? Pk : Pv;
  const void* Vm = (s == 0) ? Vq : (s == 1) ? Vk : Vv;
  __shared__ float Vl[32 * 64];
  const int tid = threadIdx.x;
  for (int i = tid; i < 2048; i += 256)
    Vl[i] = loadf(Vm, (size_t)h * 2048 + i, isf);
  __syncthreads();
  for (int kb = 0; kb < 3; ++kb) {
    const int k = kb * 256 + tid;
    float pr[32];
    const size_t prow = ((size_t)h * 768 + k) * 32;
    for (int r = 0; r < 32; ++r) pr[r] = loadf(P, prow + r, isf);
    for (int e = 0; e < 64; ++e) {
      float a = 0.f;
      for (int r = 0; r < 32; ++r) a += pr[r] * Vl[r * 64 + e];
      Wt[((size_t)sh * 64 + e) * 768 + k] = (bf16_t)a;
    }
  }
}

// ---------------------------------------------------------------------------
__global__ __launch_bounds__(256) void transpose_all_k(
    const void* Uo, const void* Vo, const void* U1, const void* V1,
    const void* U2, const void* V2, bf16_t* UoT, bf16_t* VoT, bf16_t* U1T,
    bf16_t* V1T, bf16_t* U2T, bf16_t* V2T, const int* __restrict__ flagp) {
  const int isf = *flagp;
  int t = blockIdx.x;
  const void* in;
  bf16_t* out;
  int Kd, Nd, bx, by;
  if (t < 192)       { in = Uo; out = UoT; Kd = 768;  Nd = 256;  bx = t & 7;  by = t >> 3; }
  else if (t < 384)  { t -= 192;  in = Vo; out = VoT; Kd = 256;  Nd = 768;  bx = t % 24; by = t / 24; }
  else if (t < 576)  { t -= 384;  in = U1; out = U1T; Kd = 768;  Nd = 256;  bx = t & 7;  by = t >> 3; }
  else if (t < 1344) { t -= 576;  in = V1; out = V1T; Kd = 256;  Nd = 3072; bx = t % 96; by = t / 96; }
  else if (t < 2112) { t -= 1344; in = U2; out = U2T; Kd = 3072; Nd = 256;  bx = t & 7;  by = t >> 3; }
  else               { t -= 2112; in = V2; out = V2T; Kd = 256;  Nd = 768;  bx = t % 24; by = t / 24; }
  __shared__ bf16_t tl[32][33];
  const int X = bx * 32, Y = by * 32;
  const int x = threadIdx.x & 31, y = threadIdx.x >> 5;
  for (int i = 0; i < 32; i += 8)
    tl[y + i][x] = (bf16_t)loadf(in, (size_t)(Y + y + i) * Nd + X + x, isf);
  __syncthreads();
  for (int i = 0; i < 32; i += 8)
    out[(size_t)(X + y + i) * Kd + Y + x] = tl[x][y + i];
}

// ---------------------------------------------------------------------------
// repack V1T/U2T into swizzled, linearly-stageable chunk layouts for ffn_k.
// V1S[ch][dl][c*8+j] = V1T[ch*32+dl][(c^(dl&7))*8 + j]   (ch 0..95, c 0..31)
// U2S[ch][n][c*8+j]  = U2T[n][ch*32 + (c^(n&3))*8 + j]   (c 0..3)
// ---------------------------------------------------------------------------
__global__ __launch_bounds__(256) void swz_k(const bf16_t* __restrict__ V1T,
                                             const bf16_t* __restrict__ U2T,
                                             bf16_t* __restrict__ V1S,
                                             bf16_t* __restrict__ U2S) {
  const int u = blockIdx.x * 256 + threadIdx.x;
  if (u < 98304) {
    const int ch = u >> 10, dl = (u >> 5) & 31, c = u & 31;
    *(bf16x8*)(V1S + (size_t)u * 8) =
        *(const bf16x8*)(V1T + (size_t)(ch * 32 + dl) * 256 +
                         ((c ^ (dl & 7)) * 8));
  } else {
    const int u2 = u - 98304;
    const int ch = u2 >> 10, n = (u2 >> 2) & 255, c = u2 & 3;
    *(bf16x8*)(U2S + (size_t)u2 * 8) =
        *(const bf16x8*)(U2T + (size_t)n * 3072 + ch * 32 +
                         ((c ^ (n & 3)) * 8));
  }
}

// ---------------------------------------------------------------------------
// 128x128-tile GEMM. EPI 3: QKV scatter (+biases), Q pre-scaled, V transposed
// ---------------------------------------------------------------------------
template <int EPI>
__global__ __launch_bounds__(256, 3) void gemm_bt(
    const bf16_t* __restrict__ A, const bf16_t* __restrict__ Bt, int N, int K,
    int lda, int ldb, bf16_t* __restrict__ Qb, bf16_t* __restrict__ Kb,
    bf16_t* __restrict__ Vb, const bf16_t* __restrict__ bqkv) {
  __shared__ __attribute__((aligned(16))) bf16_t As[128 * 64];
  __shared__ __attribute__((aligned(16))) bf16_t Bs[128 * 64];
  const int tid = threadIdx.x;
  const int w = tid >> 6, l = tid & 63;
  const int quad = l >> 4, l15 = l & 15;
  const int m0 = blockIdx.y * 128, n0 = blockIdx.x * 128;

  const bf16_t* gA = A + (size_t)(m0 + w * 32 + (l >> 3)) * lda + (l & 7) * 8;
  const bf16_t* gB = Bt + (size_t)(n0 + w * 32 + (l >> 3)) * ldb + (l & 7) * 8;
  bf16_t* lA = &As[(w * 32) * 64];
  bf16_t* lB = &Bs[(w * 32) * 64];

  f32x4 acc[4][4] = {};
  const int wm = (w >> 1) * 64, wn = (w & 1) * 64;

  for (int k0 = 0; k0 < K; k0 += 64) {
    for (int c = 0; c < 4; ++c) {
      GLD_TO_LDS(gA + (size_t)(c * 8) * lda + k0, lA + (c * 8) * 64);
      GLD_TO_LDS(gB + (size_t)(c * 8) * ldb + k0, lB + (c * 8) * 64);
    }
    __syncthreads();
    for (int kk = 0; kk < 2; ++kk) {
      bf16x8 af[4], bfr[4];
      for (int i = 0; i < 4; ++i)
        af[i] = *(const bf16x8*)&As[(wm + i * 16 + l15) * 64 + kk * 32 + quad * 8];
      for (int i = 0; i < 4; ++i)
        bfr[i] = *(const bf16x8*)&Bs[(wn + i * 16 + l15) * 64 + kk * 32 + quad * 8];
      for (int mi = 0; mi < 4; ++mi)
        for (int ni = 0; ni < 4; ++ni)
          acc[mi][ni] = MFMA16(af[mi], bfr[ni], acc[mi][ni]);
    }
    __syncthreads();
  }

  for (int mi = 0; mi < 4; ++mi) {
    for (int ni = 0; ni < 4; ++ni) {
      const int gn = n0 + wn + ni * 16 + l15;
      const int s = gn / 768, rem = gn - s * 768;
      const int h = rem >> 6, e = rem & 63;
      const float bvv = (float)bqkv[gn];
      for (int r = 0; r < 4; ++r) {
        const int gm = m0 + wm + mi * 16 + quad * 4 + r;
        const int b_ = gm >> 11, mloc = gm & 2047;
        const int bh = b_ * 12 + h;
        float v = acc[mi][ni][r] + bvv;
        if (s == 0) {
          Qb[((size_t)bh * 2048 + mloc) * 64 + e] = (bf16_t)(v * QSCALE);
        } else if (s == 1) {
          Kb[((size_t)bh * 2048 + mloc) * 64 + e] = (bf16_t)v;
        } else {
          Vb[((size_t)bh * 64 + e) * 2048 + mloc] = (bf16_t)v;  // transposed
        }
      }
    }
  }
}

// ---------------------------------------------------------------------------
// 64x64-tile GEMM (skinny). EPI 0: bf16 store | 8: Cf = acc (fp32)
// ---------------------------------------------------------------------------
template <int EPI>
__global__ __launch_bounds__(256, 4) void gemm64(
    const bf16_t* __restrict__ A, const bf16_t* __restrict__ Bt, int N, int K,
    int lda, int ldb, bf16_t* __restrict__ Cb, float* __restrict__ Cf) {
  __shared__ __attribute__((aligned(16))) bf16_t As[64 * 64];
  __shared__ __attribute__((aligned(16))) bf16_t Bs[64 * 64];
  const int tid = threadIdx.x;
  const int w = tid >> 6, l = tid & 63;
  const int quad = l >> 4, l15 = l & 15;
  const int m0 = blockIdx.y * 64, n0 = blockIdx.x * 64;

  const bf16_t* gA = A + (size_t)(m0 + w * 16 + (l >> 3)) * lda + (l & 7) * 8;
  const bf16_t* gB = Bt + (size_t)(n0 + w * 16 + (l >> 3)) * ldb + (l & 7) * 8;
  bf16_t* lA = &As[(w * 16) * 64];
  bf16_t* lB = &Bs[(w * 16) * 64];

  f32x4 acc[4] = {};

  for (int k0 = 0; k0 < K; k0 += 64) {
    for (int c = 0; c < 2; ++c) {
      GLD_TO_LDS(gA + (size_t)(c * 8) * lda + k0, lA + (c * 8) * 64);
      GLD_TO_LDS(gB + (size_t)(c * 8) * ldb + k0, lB + (c * 8) * 64);
    }
    __syncthreads();
    for (int kk = 0; kk < 2; ++kk) {
      bf16x8 af = *(const bf16x8*)&As[(w * 16 + l15) * 64 + kk * 32 + quad * 8];
      bf16x8 bfr[4];
      for (int i = 0; i < 4; ++i)
        bfr[i] = *(const bf16x8*)&Bs[(i * 16 + l15) * 64 + kk * 32 + quad * 8];
      for (int ni = 0; ni < 4; ++ni) acc[ni] = MFMA16(af, bfr[ni], acc[ni]);
    }
    __syncthreads();
  }

  for (int ni = 0; ni < 4; ++ni) {
    const int gn = n0 + ni * 16 + l15;
    for (int r = 0; r < 4; ++r) {
      const int gm = m0 + w * 16 + quad * 4 + r;
      if (EPI == 0)
        Cb[(size_t)gm * N + gn] = (bf16_t)acc[ni][r];
      else
        Cf[(size_t)gm * N + gn] = acc[ni][r];
    }
  }
}

// ---------------------------------------------------------------------------
// 128x64-tile GEMM for tall-skinny shapes (M large). 4 waves = 2M x 2N of
// 64x32 each; 16 MFMA/wave/K-step (2x gemm64 density). EPI 0/8 as gemm64.
// ---------------------------------------------------------------------------
template <int EPI>
__global__ __launch_bounds__(256, 3) void gemm128x64(
    const bf16_t* __restrict__ A, const bf16_t* __restrict__ Bt, int N, int K,
    int lda, int ldb, bf16_t* __restrict__ Cb, float* __restrict__ Cf) {
  __shared__ __attribute__((aligned(16))) bf16_t As[128 * 64];
  __shared__ __attribute__((aligned(16))) bf16_t Bs[64 * 64];
  const int tid = threadIdx.x;
  const int w = tid >> 6, l = tid & 63;
  const int quad = l >> 4, l15 = l & 15;
  const int m0 = blockIdx.y * 128, n0 = blockIdx.x * 64;

  const bf16_t* gA = A + (size_t)(m0 + w * 32 + (l >> 3)) * lda + (l & 7) * 8;
  const bf16_t* gB = Bt + (size_t)(n0 + w * 16 + (l >> 3)) * ldb + (l & 7) * 8;
  bf16_t* lA = &As[(w * 32) * 64];
  bf16_t* lB = &Bs[(w * 16) * 64];

  f32x4 acc[4][2] = {};
  const int wm = (w >> 1) * 64, wn = (w & 1) * 32;

  for (int k0 = 0; k0 < K; k0 += 64) {
    for (int c = 0; c < 4; ++c)
      GLD_TO_LDS(gA + (size_t)(c * 8) * lda + k0, lA + (c * 8) * 64);
    for (int c = 0; c < 2; ++c)
      GLD_TO_LDS(gB + (size_t)(c * 8) * ldb + k0, lB + (c * 8) * 64);
    __syncthreads();
    for (int kk = 0; kk < 2; ++kk) {
      bf16x8 af[4], bfr[2];
      for (int i = 0; i < 4; ++i)
        af[i] = *(const bf16x8*)&As[(wm + i * 16 + l15) * 64 + kk * 32 + quad * 8];
      for (int i = 0; i < 2; ++i)
        bfr[i] = *(const bf16x8*)&Bs[(wn + i * 16 + l15) * 64 + kk * 32 + quad * 8];
      for (int mi = 0; mi < 4; ++mi)
        for (int ni = 0; ni < 2; ++ni)
          acc[mi][ni] = MFMA16(af[mi], bfr[ni], acc[mi][ni]);
    }
    __syncthreads();
  }

  for (int mi = 0; mi < 4; ++mi) {
    for (int ni = 0; ni < 2; ++ni) {
      const int gn = n0 + wn + ni * 16 + l15;
      for (int r = 0; r < 4; ++r) {
        const int gm = m0 + wm + mi * 16 + quad * 4 + r;
        if (EPI == 0)
          Cb[(size_t)gm * N + gn] = (bf16_t)acc[mi][ni][r];
        else
          Cf[(size_t)gm * N + gn] = acc[mi][ni][r];
      }
    }
  }
}

// ---------------------------------------------------------------------------
// Flash attention, 128-row Q tiles (32 q-rows/wave), 1-D grid of 768.
// XCD-grouped block mapping: all 16 q-tiles of a head land on one XCD
// (bijective: xcd = d&7, bh = xcd*6 + (d>>3)/16, qt = (d>>3)%16) — keeps K/V
// resident in one XCD's L2 (FETCH 104.5 -> 18.5 MB, verified R5).
// Schedule: R1/R4's proven two-barrier double-buffer with counted vmcnt(4).
// ---------------------------------------------------------------------------
__global__ __launch_bounds__(256, 3) void attn_k(const bf16_t* __restrict__ Qg,
                                                 const bf16_t* __restrict__ Kg,
                                                 const bf16_t* __restrict__ Vtg,
                                                 bf16_t* __restrict__ AO) {
  // [buf 0|1][ K(64x64) | V(64x64) ]  = 32 KB
  __shared__ __attribute__((aligned(16))) bf16_t KVf[2 * 2 * 64 * 64];
  __shared__ __attribute__((aligned(16))) bf16_t Pwf[4 * 32 * 64];
  const int tid = threadIdx.x, w = tid >> 6, l = tid & 63;
  const int quad = l >> 4, l15 = l & 15;
  bf16_t* Pw = Pwf + w * 32 * 64;
  const int d = blockIdx.x;
  const int xcd = d & 7, slot = d >> 3;
  const int bh = xcd * 6 + (slot >> 4);
  const int q0 = (slot & 15) * 128;
  const size_t base = (size_t)bh * 2048 * 64;

  bf16x8 Qf[2][2];
  for (int mi = 0; mi < 2; ++mi)
    for (int kk = 0; kk < 2; ++kk)
      Qf[mi][kk] = *(const bf16x8*)(Qg + base +
                                    (size_t)(q0 + w * 32 + mi * 16 + l15) * 64 +
                                    kk * 32 + quad * 8);

  f32x4 Oa[4][2] = {};
  float lrun[2] = {0.f, 0.f};

  const int lrow = l >> 3, lc = l & 7;
  const int csw = ((lc ^ (lrow & 7)) * 8);
  const bf16_t* kg0 = Kg + base + (size_t)(w * 8 + lrow) * 64 + csw;
  const bf16_t* kg1 = kg0 + 32 * 64;
  const bf16_t* vg0 = Vtg + ((size_t)bh * 64 + w * 8 + lrow) * 2048 + csw;
  const bf16_t* vg1 = vg0 + (size_t)32 * 2048;
  const int lofs = w * 512;

  // prologue: stage tile 0 into buf 0
  GLD_TO_LDS(kg0, KVf + lofs);
  GLD_TO_LDS(kg1, KVf + 2048 + lofs);
  GLD_TO_LDS(vg0, KVf + 4096 + lofs);
  GLD_TO_LDS(vg1, KVf + 6144 + lofs);
  kg0 += 4096; kg1 += 4096; vg0 += 64; vg1 += 64;

  for (int it = 0; it < 32; ++it) {
    bf16_t* Ks = KVf + (it & 1) * 8192;
    bf16_t* Vt = Ks + 4096;
    if (it < 31) {
      // prefetch tile it+1 into the other buffer; keep 4 loads in flight
      bf16_t* Kn = KVf + ((it + 1) & 1) * 8192;
      GLD_TO_LDS(kg0, Kn + lofs);
      GLD_TO_LDS(kg1, Kn + 2048 + lofs);
      GLD_TO_LDS(vg0, Kn + 4096 + lofs);
      GLD_TO_LDS(vg1, Kn + 6144 + lofs);
      kg0 += 4096; kg1 += 4096; vg0 += 64; vg1 += 64;
      asm volatile("s_waitcnt vmcnt(4)" ::: "memory");
    } else {
      asm volatile("s_waitcnt vmcnt(0)" ::: "memory");
    }
    __builtin_amdgcn_s_barrier();
    asm volatile("" ::: "memory");

    f32x4 S[4][2] = {};
    for (int kk = 0; kk < 2; ++kk) {
      bf16x8 af[4];
      for (int nr = 0; nr < 4; ++nr) {
        const int row = nr * 16 + l15, ch = kk * 4 + quad;
        af[nr] = *(const bf16x8*)&Ks[row * 64 + ((ch ^ (row & 7)) * 8)];
      }
      __builtin_amdgcn_s_setprio(1);
      for (int nr = 0; nr < 4; ++nr)
        for (int mi = 0; mi < 2; ++mi)
          S[nr][mi] = MFMA16(af[nr], Qf[mi][kk], S[nr][mi]);
      __builtin_amdgcn_s_setprio(0);
    }

    for (int mi = 0; mi < 2; ++mi) {
      const int prow = mi * 16 + l15;
      float ps = 0.f;
      for (int nr = 0; nr < 4; ++nr) {
        float p[4];
        for (int r = 0; r < 4; ++r) {
          p[r] = exp2f(S[nr][mi][r]);
          ps += p[r];
        }
        const int nbase = nr * 16 + quad * 4;
        const int ch = nbase >> 3, nb7 = nbase & 7;
        bf16x4 pk;
        pk[0] = (bf16_t)p[0]; pk[1] = (bf16_t)p[1];
        pk[2] = (bf16_t)p[2]; pk[3] = (bf16_t)p[3];
        *(bf16x4*)&Pw[prow * 64 + ((ch ^ (prow & 7)) * 8) + nb7] = pk;
      }
      lrun[mi] += ps;
    }
    asm volatile("s_waitcnt lgkmcnt(0)" ::: "memory");

    for (int kk = 0; kk < 2; ++kk) {
      bf16x8 vf[4], pf[2];
      for (int ei = 0; ei < 4; ++ei) {
        const int row = ei * 16 + l15, ch = kk * 4 + quad;
        vf[ei] = *(const bf16x8*)&Vt[row * 64 + ((ch ^ (row & 7)) * 8)];
      }
      for (int mi = 0; mi < 2; ++mi) {
        const int prow = mi * 16 + l15, ch = kk * 4 + quad;
        pf[mi] = *(const bf16x8*)&Pw[prow * 64 + ((ch ^ (prow & 7)) * 8)];
      }
      __builtin_amdgcn_s_setprio(1);
      for (int ei = 0; ei < 4; ++ei)
        for (int mi = 0; mi < 2; ++mi)
          Oa[ei][mi] = MFMA16(vf[ei], pf[mi], Oa[ei][mi]);
      __builtin_amdgcn_s_setprio(0);
    }
    asm volatile("s_waitcnt lgkmcnt(0)" ::: "memory");
    __builtin_amdgcn_s_barrier();
    asm volatile("" ::: "memory");
  }

  for (int mi = 0; mi < 2; ++mi) {
    lrun[mi] += __shfl_xor(lrun[mi], 16);
    lrun[mi] += __shfl_xor(lrun[mi], 32);
  }

  // epilogue: O^T -> token rows via LDS (128x64), coalesced write
  bf16_t* Os = KVf;
  const float inv0 = 1.f / lrun[0], inv1 = 1.f / lrun[1];
  for (int mi = 0; mi < 2; ++mi) {
    const float inv = mi ? inv1 : inv0;
    const int mrow = w * 32 + mi * 16 + l15;
    for (int ei = 0; ei < 4; ++ei) {
      const int e0 = ei * 16 + quad * 4;
      const int ch = e0 >> 3, e7 = e0 & 7;
      bf16x4 q;
      q[0] = (bf16_t)(Oa[ei][mi][0] * inv);
      q[1] = (bf16_t)(Oa[ei][mi][1] * inv);
      q[2] = (bf16_t)(Oa[ei][mi][2] * inv);
      q[3] = (bf16_t)(Oa[ei][mi][3] * inv);
      *(bf16x4*)&Os[mrow * 64 + ((ch ^ (mrow & 7)) * 8) + e7] = q;
    }
  }
  __syncthreads();
  const int b_ = bh / 12, h_ = bh % 12;
  const int row = tid >> 1;
  for (int c = 0; c < 4; ++c) {
    const int ch = (tid & 1) * 4 + c;
    bf16x8 dd = *(const bf16x8*)&Os[row * 64 + ((ch ^ (row & 7)) * 8)];
    *(bf16x8*)(AO + ((size_t)(b_ * 2048 + q0 + row)) * 768 + h_ * 64 + ch * 8) = dd;
  }
}

// ---------------------------------------------------------------------------
// Fused FFN middle: per block (64 tokens, dff group g of 768):
//   loop 24 chunks of 32 dff: Ht = V1c(A) x mid(B) -> +b1, gelu -> LDS ->
//   acc[tok][256] += H x U2c.  acc stays in registers; write bf16 slice.
// Double-buffered V1/U2 staging, counted vmcnt(8), two barriers per chunk
// (R1-R4's proven schedule).
// ---------------------------------------------------------------------------
__global__ __launch_bounds__(256, 2) void ffn_k(const bf16_t* __restrict__ mid,
                                                const bf16_t* __restrict__ V1S,
                                                const bf16_t* __restrict__ U2S,
                                                const bf16_t* __restrict__ b1c,
                                                bf16_t* __restrict__ T2s) {
  __shared__ __attribute__((aligned(16))) bf16_t V1l[2][32 * 256];
  __shared__ __attribute__((aligned(16))) bf16_t U2l[2][256 * 32];
  __shared__ __attribute__((aligned(16))) bf16_t Hl[4][16 * 32];
  __shared__ __attribute__((aligned(16))) bf16_t Bl[768];
  const int tid = threadIdx.x, w = tid >> 6, l = tid & 63;
  const int quad = l >> 4, l15 = l & 15;
  const int m0 = blockIdx.x * 64;
  const int g = blockIdx.y;

  if (tid < 96)
    *(bf16x8*)&Bl[tid * 8] = *(const bf16x8*)(b1c + g * 768 + tid * 8);

  bf16x8 mf[8];
  for (int kk = 0; kk < 8; ++kk)
    mf[kk] = *(const bf16x8*)(mid + (size_t)(m0 + w * 16 + l15) * 256 +
                              kk * 32 + quad * 8);

  f32x4 acc[16] = {};

  const bf16_t* vs = V1S + (size_t)g * 24 * 8192 + w * 512 + l * 8;
  const bf16_t* us = U2S + (size_t)g * 24 * 8192 + w * 512 + l * 8;
  const int lofs = w * 512;

  // prologue: stage chunk 0 into buf 0
  for (int i = 0; i < 4; ++i) {
    GLD_TO_LDS(vs + i * 2048, V1l[0] + lofs + i * 2048);
    GLD_TO_LDS(us + i * 2048, U2l[0] + lofs + i * 2048);
  }
  vs += 8192; us += 8192;

  for (int c = 0; c < 24; ++c) {
    const int cb = c & 1;
    if (c < 23) {
      // prefetch chunk c+1 into the other buffer; keep 8 loads in flight
      for (int i = 0; i < 4; ++i) {
        GLD_TO_LDS(vs + i * 2048, V1l[cb ^ 1] + lofs + i * 2048);
        GLD_TO_LDS(us + i * 2048, U2l[cb ^ 1] + lofs + i * 2048);
      }
      vs += 8192; us += 8192;
      asm volatile("s_waitcnt vmcnt(8)" ::: "memory");
    } else {
      asm volatile("s_waitcnt vmcnt(0)" ::: "memory");
    }
    __builtin_amdgcn_s_barrier();
    asm volatile("" ::: "memory");

    // GEMM1: Ht[d][tok]
    f32x4 S[2] = {};
    for (int kk = 0; kk < 8; ++kk) {
      const int ck = kk * 4 + quad;
      bf16x8 a0 = *(const bf16x8*)&V1l[cb][l15 * 256 + ((ck ^ (l15 & 7)) * 8)];
      bf16x8 a1 =
          *(const bf16x8*)&V1l[cb][(16 + l15) * 256 + ((ck ^ (l15 & 7)) * 8)];
      __builtin_amdgcn_s_setprio(1);
      S[0] = MFMA16(a0, mf[kk], S[0]);
      S[1] = MFMA16(a1, mf[kk], S[1]);
      __builtin_amdgcn_s_setprio(0);
    }
    // bias + gelu, pack into Hl[tok][dff]
    for (int mt = 0; mt < 2; ++mt) {
      bf16x4 bb = *(const bf16x4*)&Bl[c * 32 + mt * 16 + quad * 4];
      bf16x4 hv;
      for (int r = 0; r < 4; ++r) {
        const float v = S[mt][r] + (float)bb[r];
        const float z2 = 2.302589f * (v + 0.044715f * v * v * v);
        hv[r] = (bf16_t)(v / (1.f + exp2f(-z2)));
      }
      const int hch = mt * 2 + (quad >> 1);
      *(bf16x4*)&Hl[w][l15 * 32 + ((hch ^ (l15 & 3)) * 8) + (quad & 1) * 4] = hv;
    }
    asm volatile("s_waitcnt lgkmcnt(0)" ::: "memory");

    // GEMM2: acc[tok][n] += H x U2c
    bf16x8 pa = *(const bf16x8*)&Hl[w][l15 * 32 + ((quad ^ (l15 & 3)) * 8)];
    __builtin_amdgcn_s_setprio(1);
    for (int ni = 0; ni < 16; ++ni) {
      const int n = ni * 16 + l15;
      bf16x8 bfr = *(const bf16x8*)&U2l[cb][n * 32 + ((quad ^ (n & 3)) * 8)];
      acc[ni] = MFMA16(pa, bfr, acc[ni]);
    }
    __builtin_amdgcn_s_setprio(0);
    asm volatile("s_waitcnt lgkmcnt(0)" ::: "memory");
    __builtin_amdgcn_s_barrier();
    asm volatile("" ::: "memory");
  }

  bf16_t* outp = T2s + ((size_t)g * 8192 + m0 + w * 16 + quad * 4) * 256;
  for (int ni = 0; ni < 16; ++ni)
    for (int r = 0; r < 4; ++r)
      outp[(size_t)r * 256 + ni * 16 + l15] = (bf16_t)acc[ni][r];
}

// sum 4 bf16 slices -> bf16
__global__ __launch_bounds__(256) void sum4_k(const bf16_t* __restrict__ T2s,
                                              bf16_t* __restrict__ out) {
  const size_t i = ((size_t)blockIdx.x * 256 + threadIdx.x) * 4;
  f32x4 s = {};
  for (int g = 0; g < 4; ++g) {
    bf16x4 v = *(const bf16x4*)(T2s + (size_t)g * 2097152 + i);
    for (int r = 0; r < 4; ++r) s[r] += (float)v[r];
  }
  bf16x4 o;
  for (int r = 0; r < 4; ++r) o[r] = (bf16_t)s[r];
  *(bf16x4*)(out + i) = o;
}

// ---------------------------------------------------------------------------
// Fused residual + bias + LayerNorm.
// ---------------------------------------------------------------------------
__global__ __launch_bounds__(256) void lnf_k(
    const float* __restrict__ Acc, const void* __restrict__ resid,
    const int* __restrict__ rflag, const bf16_t* __restrict__ bias,
    const bf16_t* __restrict__ g, const bf16_t* __restrict__ b, void* out,
    const int* __restrict__ oflag) {
  const int wv = threadIdx.x >> 6, l = threadIdx.x & 63;
  const int row = blockIdx.x * 4 + wv;
  const int risf = rflag ? *rflag : 0;
  const int f32out = oflag ? *oflag : 0;
  float v[12], s = 0.f, s2 = 0.f;
  for (int j = 0; j < 3; ++j) {
    const int c0 = j * 256 + l * 4;
    const f32x4 a = *(const f32x4*)(Acc + (size_t)row * 768 + c0);
    for (int r = 0; r < 4; ++r) {
      const float f = a[r] + (float)bias[c0 + r] +
                      loadf(resid, (size_t)row * 768 + c0 + r, risf);
      v[j * 4 + r] = f;
      s += f;
      s2 += f * f;
    }
  }
  for (int m = 32; m; m >>= 1) {
    s += __shfl_xor(s, m);
    s2 += __shfl_xor(s2, m);
  }
  const float mu = s * (1.f / 768.f);
  const float var = s2 * (1.f / 768.f) - mu * mu;
  const float rs = rsqrtf(var + 1e-5f);
  for (int j = 0; j < 3; ++j) {
    const int c0 = j * 256 + l * 4;
    if (f32out) {
      f32x4 o;
      for (int r = 0; r < 4; ++r)
        o[r] = (v[j * 4 + r] - mu) * rs * (float)g[c0 + r] + (float)b[c0 + r];
      *(f32x4*)((float*)out + (size_t)row * 768 + c0) = o;
    } else {
      bf16x4 o;
      for (int r = 0; r < 4; ++r)
        o[r] = (bf16_t)((v[j * 4 + r] - mu) * rs * (float)g[c0 + r] +
                        (float)b[c0 + r]);
      *(bf16x4*)((bf16_t*)out + (size_t)row * 768 + c0) = o;
    }
  }
}

// ---------------------------------------------------------------------------
extern "C" void kernel_launch(void* const* d_in, const int* in_sizes, int n_in,
                              void* d_out, int out_size, void* d_ws,
                              size_t ws_size, hipStream_t stream) {
  const void* x   = d_in[0];
  const void* Pq  = d_in[2];
  const void* Vq  = d_in[3];
  const void* bq  = d_in[4];
  const void* Pk  = d_in[5];
  const void* Vk  = d_in[6];
  const void* bk  = d_in[7];
  const void* Pv  = d_in[8];
  const void* Vv  = d_in[9];
  const void* bv  = d_in[10];
  const void* Uo  = d_in[11];
  const void* Vo  = d_in[12];
  const void* bo  = d_in[13];
  const void* U1  = d_in[14];
  const void* V1  = d_in[15];
  const void* b1  = d_in[16];
  const void* U2  = d_in[17];
  const void* V2  = d_in[18];
  const void* b2  = d_in[19];
  const void* g1  = d_in[20];
  const void* be1 = d_in[21];
  const void* g2  = d_in[22];
  const void* be2 = d_in[23];

  // ---- workspace layout, peak 60,182,528 B ----
  char* ws = (char*)d_ws;
  bf16_t* WtQKV = (bf16_t*)(ws + 0);
  bf16_t* UoT   = (bf16_t*)(ws + 3538944);
  bf16_t* VoT   = (bf16_t*)(ws + 3932160);
  bf16_t* U1T   = (bf16_t*)(ws + 4325376);
  bf16_t* V1T   = (bf16_t*)(ws + 4718592);
  bf16_t* U2T   = (bf16_t*)(ws + 6291456);
  bf16_t* V2T   = (bf16_t*)(ws + 7864320);
  bf16_t* Bc    = (bf16_t*)(ws + 8257536);
  int*    flag  = (int*)(ws + 8277504);
  bf16_t* xc    = (bf16_t*)(ws + 8278016);    // 12.58 MB
  bf16_t* Qb    = (bf16_t*)(ws + 20860928);   // 12.58 MB
  bf16_t* Kb    = (bf16_t*)(ws + 33443840);   // 12.58 MB
  bf16_t* Vb    = (bf16_t*)(ws + 46026752);   // -> 58,609,664
  bf16_t* WoT   = (bf16_t*)(ws + 58609664);   // -> 59,789,312
  bf16_t* Uo_c  = (bf16_t*)(ws + 59789312);   // -> 60,182,528
  // aliases (after attention, Qb/Kb/Vb dead):
  bf16_t* AO   = xc;                           // attn out over dead xc
  bf16_t* X1   = AO;                           // LN1 out in place
  bf16_t* T    = Qb;                           // mid / t2 bf16 4.2 MB
  bf16_t* T2s  = (bf16_t*)(ws + 25055232);    // 4 x 4.19 MB -> 41,832,448
  bf16_t* V1S  = (bf16_t*)(ws + 41832448);    // 1.5 MB
  bf16_t* U2S  = (bf16_t*)(ws + 43405312);    // 1.5 MB -> 44,978,176
  float*  Rf   = (float*)(ws + 33443840);     // fp32 25.2 MB (Kb+Vb slots)

  bf16_t* bqkvc = Bc + 0;
  bf16_t* boc   = Bc + 2304;
  bf16_t* b1c   = Bc + 3072;
  bf16_t* b2c   = Bc + 6144;
  bf16_t* g1c   = Bc + 6912;
  bf16_t* be1c  = Bc + 7680;
  bf16_t* g2c   = Bc + 8448;
  bf16_t* be2c  = Bc + 9216;

  // ---- dtype detection + canonicalization + weight prep ----
  detect_k<<<1, 256, 0, stream>>>((const unsigned short*)x, flag);
  cvtin_k<<<4096, 256, 0, stream>>>(x, xc, 8192 * 768, flag);
  cvtin_k<<<768, 256, 0, stream>>>(Uo, Uo_c, 768 * 256, flag);
  bcat_k<<<39, 256, 0, stream>>>(bq, bk, bv, bo, b1, b2, g1, be1, g2, be2, Bc,
                                 flag);
  wqkv_k<<<36, 256, 0, stream>>>(Pq, Vq, Pk, Vk, Pv, Vv, WtQKV, flag);
  transpose_all_k<<<2304, 256, 0, stream>>>(Uo, Vo, U1, V1, U2, V2, UoT, VoT,
                                            U1T, V1T, U2T, V2T, flag);
  gemm64<0><<<dim3(12, 12), 256, 0, stream>>>(VoT, Uo_c, 768, 256, 256, 256,
                                              WoT, nullptr);

  // ---- QKV projection (Q pre-scaled) ----
  gemm_bt<3><<<dim3(18, 64), 256, 0, stream>>>(xc, WtQKV, 2304, 768, 768, 768,
                                               Qb, Kb, Vb, bqkvc);

  // ---- flash attention -> AO ----
  attn_k<<<768, 256, 0, stream>>>(Qb, Kb, Vb, AO);

  // ---- output projection: Rf = AO@WoT; X1 = LN(x + Rf + bo) ----
  gemm128x64<8><<<dim3(12, 64), 256, 0, stream>>>(AO, WoT, 768, 768, 768, 768,
                                                  nullptr, Rf);
  lnf_k<<<2048, 256, 0, stream>>>(Rf, x, flag, boc, g1c, be1c, X1, nullptr);

  // ---- FFN: mid = X1@U1; fused gelu+U2 contraction; t2@V2; LN2 ----
  swz_k<<<768, 256, 0, stream>>>(V1T, U2T, V1S, U2S);
  gemm64<0><<<dim3(4, 128), 256, 0, stream>>>(X1, U1T, 256, 768, 768, 768, T,
                                              nullptr);
  ffn_k<<<dim3(128, 4), 256, 0, stream>>>(T, V1S, U2S, b1c, T2s);
  sum4_k<<<2048, 256, 0, stream>>>(T2s, T);
  gemm128x64<8><<<dim3(12, 64), 256, 0, stream>>>(T, V2T, 768, 256, 256, 256,
                                                  nullptr, Rf);
  lnf_k<<<2048, 256, 0, stream>>>(Rf, X1, nullptr, b2c, g2c, be2c, d_out, flag);
}